// Round 12
// baseline (383.302 us; speedup 1.0000x reference)
//
#include <hip/hip_runtime.h>

#define NREL 8

typedef __attribute__((ext_vector_type(8))) short bf16x8;
typedef __attribute__((ext_vector_type(4))) float f32x4;

__device__ inline ushort f2bf(float f)
{
    union { float f; unsigned u; } v; v.f = f;
    unsigned r = v.u + 0x7FFF + ((v.u >> 16) & 1);   // RNE
    return (ushort)(r >> 16);
}

// ---------------------------------------------------------------------------
// zero16: graph-capturable memset replacement (round-2 lesson).
// ---------------------------------------------------------------------------
__global__ __launch_bounds__(256) void zero16(float4* __restrict__ p, int n4)
{
    int i = blockIdx.x * 256 + threadIdx.x;
    int stride = gridDim.x * 256;
    for (; i < n4; i += stride) p[i] = make_float4(0.f, 0.f, 0.f, 0.f);
}

// ---------------------------------------------------------------------------
// CSR build: count -> dst totals -> 3-kernel multi-block scan -> fill.
// ---------------------------------------------------------------------------
__global__ __launch_bounds__(256) void count_edges(
    const int* __restrict__ ei, const int* __restrict__ et,
    int* __restrict__ cnt, int E, int N)
{
    int e = blockIdx.x * 256 + threadIdx.x;
    if (e < E) {
        int d = ei[E + e];
        int r = et[e];
        atomicAdd(&cnt[r * N + d], 1);
    }
}

__global__ __launch_bounds__(256) void dst_counts(
    const int* __restrict__ cnt, int* __restrict__ dcnt, int N)
{
    int d = blockIdx.x * 256 + threadIdx.x;
    if (d < N) {
        int s = 0;
        #pragma unroll
        for (int r = 0; r < NREL; r++) s += cnt[r * N + d];
        dcnt[d] = s;
    }
}

__global__ __launch_bounds__(256) void scan1(
    const int* __restrict__ in, int* __restrict__ part,
    int* __restrict__ bsum, int n)
{
    __shared__ int tmp[256];
    int i = blockIdx.x * 256 + threadIdx.x;
    int v = (i < n) ? in[i] : 0;
    tmp[threadIdx.x] = v;
    __syncthreads();
    for (int off = 1; off < 256; off <<= 1) {
        int t = (threadIdx.x >= off) ? tmp[threadIdx.x - off] : 0;
        __syncthreads();
        tmp[threadIdx.x] += t;
        __syncthreads();
    }
    if (i < n) part[i] = tmp[threadIdx.x] - v;
    if (threadIdx.x == 255) bsum[blockIdx.x] = tmp[255];
}

__global__ __launch_bounds__(1024) void scan2(int* __restrict__ bsum, int nb)
{
    __shared__ int tmp[1024];
    int tid = threadIdx.x;
    int v = (tid < nb) ? bsum[tid] : 0;
    tmp[tid] = v;
    __syncthreads();
    for (int off = 1; off < 1024; off <<= 1) {
        int t = (tid >= off) ? tmp[tid - off] : 0;
        __syncthreads();
        tmp[tid] += t;
        __syncthreads();
    }
    if (tid < nb) bsum[tid] = tmp[tid] - v;
}

__global__ __launch_bounds__(256) void scan3(
    const int* __restrict__ part, const int* __restrict__ bsum,
    int* __restrict__ rowptr, int* __restrict__ cursor, int n, int E)
{
    int i = blockIdx.x * 256 + threadIdx.x;
    if (i < n) {
        int v = part[i] + bsum[blockIdx.x];
        rowptr[i] = v;
        cursor[i] = v;
    }
    if (i == 0) rowptr[n] = E;
}

__global__ __launch_bounds__(256) void fill_csr(
    const int* __restrict__ ei, const int* __restrict__ et,
    int* __restrict__ cursor, int* __restrict__ spk, int E)
{
    int e = blockIdx.x * 256 + threadIdx.x;
    if (e < E) {
        int d = ei[E + e];
        int pos = atomicAdd(&cursor[d], 1);
        spk[pos] = ei[e] | (et[e] << 20);
    }
}

// ---------------------------------------------------------------------------
// conv_x: fp32 activations -> bf16, contiguous.
// ---------------------------------------------------------------------------
__global__ __launch_bounds__(256) void conv_x(
    const float* __restrict__ x, ushort* __restrict__ xb, int n4)
{
    int i = blockIdx.x * 256 + threadIdx.x;
    int stride = gridDim.x * 256;
    for (; i < n4; i += stride) {
        float4 v = ((const float4*)x)[i];
        ushort4 o;
        o.x = f2bf(v.x); o.y = f2bf(v.y); o.z = f2bf(v.z); o.w = f2bf(v.w);
        ((ushort4*)xb)[i] = o;
    }
}

// ---------------------------------------------------------------------------
// conv_wf: weights -> bf16 in MFMA-fragment order (round-9 win).
// ---------------------------------------------------------------------------
__global__ __launch_bounds__(256) void conv_wf(
    const float* __restrict__ W, const float* __restrict__ root,
    ushort* __restrict__ Wf)
{
    int i = blockIdx.x * 256 + threadIdx.x;
    if (i >= 128 * 1152) return;
    int f = i >> 9;
    int within = i & 511;
    int l = within >> 3;
    int j = within & 7;
    int rs = f >> 5;
    int kk = (f >> 3) & 3;
    int n  = f & 7;
    int col = (n << 4) | (l & 15);
    int kl  = kk * 32 + (l >> 4) * 8 + j;
    float v = (rs < 8) ? W[rs * 16384 + kl * 128 + col] : root[kl * 128 + col];
    Wf[i] = f2bf(v);
}

// ---------------------------------------------------------------------------
// FUSED gather + 9-source MFMA GEMM (round-12: aggX never touches memory).
// Round-11 evidence: gather was bound by the 100MB aggX write (1.56 TB/s
// drain = the whole 64us), and rgemm re-read it. Fusion keeps relation sums
// in regs -> 32KB swizzled LDS -> A-fragments, killing ~400MB of HBM traffic.
//
// Block = 256 thr = 4 waves, owns 16 dst rows (N % 16 == 0 for this problem).
// Phase 1: wave wid gathers rows wid*4..wid*4+3 (8 rel sums in 16 VGPRs,
//   proven 4-deep readlane batch), writes bf16 to LDS [rs][row16][128] with
//   XOR swizzle byte^=(row&7)<<4 (both sides, rule #21; read = 2-way = free).
// Phase 2: one barrier; A-frag = ds_read_b128 (row=lane&15, k=kk*32+kgrp*8),
//   B-frag = fragment-ordered Wf (L2-resident); wave computes n-blocks
//   {wid*2, wid*2+1}; acc = 2 x f32x4. rs=8 (root) A direct from global Xb.
// ---------------------------------------------------------------------------
__global__ __launch_bounds__(256) void fused_layer(
    const ushort* __restrict__ Xb, const int* __restrict__ rowptr,
    const int* __restrict__ spk, const int* __restrict__ cnt,
    const ushort* __restrict__ Wf, const float* __restrict__ bias,
    float* __restrict__ Ofp, ushort* __restrict__ Obf, int N, int relu)
{
    __shared__ ushort lds[8 * 16 * 128];   // 32 KB

    int wid  = threadIdx.x >> 6;
    int lane = threadIdx.x & 63;
    int blk0 = blockIdx.x * 16;

    // ---------------- phase 1: gather 4 rows per wave ----------------
    #pragma unroll 1
    for (int rr = 0; rr < 4; rr++) {
        int lrow16 = wid * 4 + rr;
        int d = blk0 + lrow16;

        float2 a0 = {0.f, 0.f}, a1 = {0.f, 0.f}, a2 = {0.f, 0.f}, a3 = {0.f, 0.f};
        float2 a4 = {0.f, 0.f}, a5 = {0.f, 0.f}, a6 = {0.f, 0.f}, a7 = {0.f, 0.f};

        #define ROWLD(P) \
            (((const unsigned*)(Xb + (size_t)((P) & 0xFFFFF) * 128))[lane])
        #define CONSUME(P, U)                                               \
        {                                                                   \
            union { unsigned u; float f; } lo, hi;                          \
            lo.u = (U) << 16; hi.u = (U) & 0xFFFF0000u;                     \
            switch ((P) >> 20) {                                            \
                case 0: a0.x += lo.f; a0.y += hi.f; break;                  \
                case 1: a1.x += lo.f; a1.y += hi.f; break;                  \
                case 2: a2.x += lo.f; a2.y += hi.f; break;                  \
                case 3: a3.x += lo.f; a3.y += hi.f; break;                  \
                case 4: a4.x += lo.f; a4.y += hi.f; break;                  \
                case 5: a5.x += lo.f; a5.y += hi.f; break;                  \
                case 6: a6.x += lo.f; a6.y += hi.f; break;                  \
                default: a7.x += lo.f; a7.y += hi.f; break;                 \
            }                                                               \
        }

        if (d < N) {
            int beg = rowptr[d], end = rowptr[d + 1];
            int i = beg;
            for (; i + 4 <= end; i += 4) {
                int pk4 = spk[i + (lane & 3)];
                int p0 = __builtin_amdgcn_readlane(pk4, 0);
                int p1 = __builtin_amdgcn_readlane(pk4, 1);
                int p2 = __builtin_amdgcn_readlane(pk4, 2);
                int p3 = __builtin_amdgcn_readlane(pk4, 3);
                unsigned u0 = ROWLD(p0);
                unsigned u1 = ROWLD(p1);
                unsigned u2 = ROWLD(p2);
                unsigned u3 = ROWLD(p3);
                CONSUME(p0, u0);
                CONSUME(p1, u1);
                CONSUME(p2, u2);
                CONSUME(p3, u3);
            }
            for (; i < end; i++) {
                int p = __builtin_amdgcn_readfirstlane(spk[i]);
                unsigned u = ROWLD(p);
                CONSUME(p, u);
            }
        }
        #undef CONSUME
        #undef ROWLD

        // scale by 1/cnt, cvt bf16, swizzled LDS write (conflict-free)
        unsigned swz = (unsigned)(lrow16 & 7) << 4;
        char* rowbase = (char*)lds + (lrow16 << 8);
        #define WR2(R, A)                                                   \
        {                                                                   \
            int c = (d < N) ? cnt[R * N + d] : 0;                           \
            float inv = (c > 0) ? 1.f / (float)c : 0.f;                     \
            unsigned pk = (unsigned)f2bf(A.x * inv)                         \
                        | ((unsigned)f2bf(A.y * inv) << 16);                \
            *(unsigned*)(rowbase + (R << 12) +                              \
                         ((((unsigned)lane << 2)) ^ swz)) = pk;             \
        }
        WR2(0, a0) WR2(1, a1) WR2(2, a2) WR2(3, a3)
        WR2(4, a4) WR2(5, a5) WR2(6, a6) WR2(7, a7)
        #undef WR2
    }
    __syncthreads();

    // ---------------- phase 2: MFMA over K = 9*128 ----------------
    int lrow = lane & 15;
    int kgrp = lane >> 4;
    unsigned swzR = (unsigned)(lrow & 7) << 4;
    const bf16x8* Wf8 = (const bf16x8*)Wf;
    int n0 = wid * 2;

    f32x4 acc0 = {0.f, 0.f, 0.f, 0.f};
    f32x4 acc1 = {0.f, 0.f, 0.f, 0.f};
    const char* abase = (const char*)lds + (lrow << 8);

    #pragma unroll 1
    for (int rs = 0; rs < 8; rs++) {
        const bf16x8* Bp = Wf8 + (size_t)rs * 2048 + (size_t)n0 * 64 + lane;
        #pragma unroll
        for (int kk = 0; kk < 4; kk++) {
            bf16x8 a = *(const bf16x8*)(abase + (rs << 12) +
                         (((unsigned)(kk * 64 + kgrp * 16)) ^ swzR));
            bf16x8 b0 = Bp[kk * 512];
            bf16x8 b1 = Bp[kk * 512 + 64];
            acc0 = __builtin_amdgcn_mfma_f32_16x16x32_bf16(a, b0, acc0, 0, 0, 0);
            acc1 = __builtin_amdgcn_mfma_f32_16x16x32_bf16(a, b1, acc1, 0, 0, 0);
        }
    }
    {   // rs = 8: root source, A direct from global Xb
        int arow = blk0 + lrow; if (arow >= N) arow = N - 1;
        const ushort* A = Xb + (size_t)arow * 128;
        const bf16x8* Bp = Wf8 + (size_t)8 * 2048 + (size_t)n0 * 64 + lane;
        #pragma unroll
        for (int kk = 0; kk < 4; kk++) {
            bf16x8 a = *(const bf16x8*)(A + kk * 32 + kgrp * 8);
            bf16x8 b0 = Bp[kk * 512];
            bf16x8 b1 = Bp[kk * 512 + 64];
            acc0 = __builtin_amdgcn_mfma_f32_16x16x32_bf16(a, b0, acc0, 0, 0, 0);
            acc1 = __builtin_amdgcn_mfma_f32_16x16x32_bf16(a, b1, acc1, 0, 0, 0);
        }
    }

    // epilogue (D: col=lane&15, row=(lane>>4)*4+reg)
    int row0 = blk0 + kgrp * 4;
    #define EPI(ACC, NN)                                                    \
    {                                                                       \
        int col = (NN) * 16 + lrow;                                         \
        float bv = bias[col];                                               \
        _Pragma("unroll")                                                   \
        for (int r = 0; r < 4; r++) {                                       \
            int row = row0 + r;                                             \
            if (row < N) {                                                  \
                float v = ACC[r] + bv;                                      \
                if (relu) v = fmaxf(v, 0.f);                                \
                if (Ofp) Ofp[(size_t)row * 128 + col] = v;                  \
                if (Obf) Obf[(size_t)row * 128 + col] = f2bf(v);            \
            }                                                               \
        }                                                                   \
    }
    EPI(acc0, n0)
    EPI(acc1, n0 + 1)
    #undef EPI
}

// ---------------------------------------------------------------------------
// out[n][c] = sum_k emb[n][k] * Wc[k*16+c] + bc[c];   16 nodes / block
// ---------------------------------------------------------------------------
__global__ __launch_bounds__(256) void classifier(
    const float* __restrict__ emb, const float* __restrict__ Wc,
    const float* __restrict__ bc, float* __restrict__ out, int N)
{
    int t = threadIdx.x;
    int c = t & 15;
    int n = blockIdx.x * 16 + (t >> 4);
    if (n >= N) return;
    const float* e = emb + (size_t)n * 128;
    float acc = bc[c];
    #pragma unroll 8
    for (int k = 0; k < 128; k++) acc += e[k] * Wc[k * 16 + c];
    out[(size_t)n * 16 + c] = acc;
}

static inline size_t align256(size_t x) { return (x + 255) & ~(size_t)255; }

extern "C" void kernel_launch(void* const* d_in, const int* in_sizes, int n_in,
                              void* d_out, int out_size, void* d_ws, size_t ws_size,
                              hipStream_t stream)
{
    const float* x     = (const float*)d_in[0];
    const int*   ei    = (const int*)d_in[1];
    const int*   et    = (const int*)d_in[2];
    const float* W1    = (const float*)d_in[3];
    const float* root1 = (const float*)d_in[4];
    const float* b1    = (const float*)d_in[5];
    const float* W2    = (const float*)d_in[6];
    const float* root2 = (const float*)d_in[7];
    const float* b2    = (const float*)d_in[8];
    const float* Wc    = (const float*)d_in[9];
    const float* bc    = (const float*)d_in[10];

    const int N = in_sizes[0] / 128;
    const int E = in_sizes[2];
    const int C = in_sizes[10];   // 16

    float* out = (float*)d_out;                 // [N,16]
    float* emb = out + (size_t)N * C;           // [N,128] fp32 (2nd output)

    // ws: cnt | rowptr | cursor | part | bsum | spk | xb | hb | Wf1 | Wf2
    size_t cntB  = align256((size_t)NREL * N * sizeof(int));
    size_t rpB   = align256((size_t)(N + 1) * sizeof(int));
    size_t curB  = align256((size_t)N * sizeof(int));
    size_t bsB   = align256((size_t)1024 * sizeof(int));
    size_t spkB  = align256((size_t)E * sizeof(int));
    size_t xbB   = align256((size_t)N * 128 * sizeof(ushort));
    size_t wtB   = align256((size_t)128 * 1152 * sizeof(ushort));

    char* p = (char*)d_ws;
    int*    cnt    = (int*)p;      p += cntB;
    int*    rowptr = (int*)p;      p += rpB;
    int*    cursor = (int*)p;      p += curB;
    int*    part   = (int*)p;      p += curB;
    int*    bsum   = (int*)p;      p += bsB;
    int*    spk    = (int*)p;      p += spkB;
    ushort* xb     = (ushort*)p;   p += xbB;
    ushort* hb     = (ushort*)p;   p += xbB;
    ushort* Wf1    = (ushort*)p;   p += wtB;
    ushort* Wf2    = (ushort*)p;

    dim3 blk(256);
    int gE    = (E + 255) / 256;
    int gN    = (N + 255) / 256;     // <=1024 for scan2
    int gFus  = (N + 15) / 16;       // 3125
    int gCls  = (N + 15) / 16;
    int gWt   = (128 * 1152 + 255) / 256;
    long long cnt4 = (long long)NREL * N / 4;
    int gZ = (int)((cnt4 + 255) / 256); if (gZ > 2048) gZ = 2048;
    int nx4 = N * 32;
    int gCx = (nx4 + 255) / 256; if (gCx > 2048) gCx = 2048;

    // ---- CSR build (shared by both layers) ----
    zero16<<<gZ, blk, 0, stream>>>((float4*)cnt, (int)cnt4);
    count_edges<<<gE, blk, 0, stream>>>(ei, et, cnt, E, N);
    dst_counts<<<gN, blk, 0, stream>>>(cnt, cursor, N);
    scan1<<<gN, blk, 0, stream>>>(cursor, part, bsum, N);
    scan2<<<1, 1024, 0, stream>>>(bsum, gN);
    scan3<<<gN, blk, 0, stream>>>(part, bsum, rowptr, cursor, N, E);
    fill_csr<<<gE, blk, 0, stream>>>(ei, et, cursor, spk, E);

    // ---- bf16 conversions ----
    conv_x<<<gCx, blk, 0, stream>>>(x, xb, nx4);
    conv_wf<<<gWt, blk, 0, stream>>>(W1, root1, Wf1);
    conv_wf<<<gWt, blk, 0, stream>>>(W2, root2, Wf2);

    // ---- layer 1: fused gather+GEMM -> hb (bf16, relu) ----
    fused_layer<<<gFus, blk, 0, stream>>>(xb, rowptr, spk, cnt, Wf1, b1,
                                          nullptr, hb, N, 1);

    // ---- layer 2: fused gather+GEMM -> emb (fp32) ----
    fused_layer<<<gFus, blk, 0, stream>>>(hb, rowptr, spk, cnt, Wf2, b2,
                                          emb, nullptr, N, 0);

    // ---- classifier ----
    classifier<<<gCls, blk, 0, stream>>>(emb, Wc, bc, out, N);
}

// Round 13
// 325.520 us; speedup vs baseline: 1.1775x; 1.1775x over previous
//
#include <hip/hip_runtime.h>

#define NREL 8

typedef __attribute__((ext_vector_type(8))) short bf16x8;
typedef __attribute__((ext_vector_type(4))) float f32x4;

__device__ inline ushort f2bf(float f)
{
    union { float f; unsigned u; } v; v.f = f;
    unsigned r = v.u + 0x7FFF + ((v.u >> 16) & 1);   // RNE
    return (ushort)(r >> 16);
}

// ---------------------------------------------------------------------------
// zero16: graph-capturable memset replacement (round-2 lesson).
// ---------------------------------------------------------------------------
__global__ __launch_bounds__(256) void zero16(float4* __restrict__ p, int n4)
{
    int i = blockIdx.x * 256 + threadIdx.x;
    int stride = gridDim.x * 256;
    for (; i < n4; i += stride) p[i] = make_float4(0.f, 0.f, 0.f, 0.f);
}

// ---------------------------------------------------------------------------
// CSR build: count -> dst totals -> 3-kernel multi-block scan -> fill.
// ---------------------------------------------------------------------------
__global__ __launch_bounds__(256) void count_edges(
    const int* __restrict__ ei, const int* __restrict__ et,
    int* __restrict__ cnt, int E, int N)
{
    int e = blockIdx.x * 256 + threadIdx.x;
    if (e < E) {
        int d = ei[E + e];
        int r = et[e];
        atomicAdd(&cnt[r * N + d], 1);
    }
}

__global__ __launch_bounds__(256) void dst_counts(
    const int* __restrict__ cnt, int* __restrict__ dcnt, int N)
{
    int d = blockIdx.x * 256 + threadIdx.x;
    if (d < N) {
        int s = 0;
        #pragma unroll
        for (int r = 0; r < NREL; r++) s += cnt[r * N + d];
        dcnt[d] = s;
    }
}

__global__ __launch_bounds__(256) void scan1(
    const int* __restrict__ in, int* __restrict__ part,
    int* __restrict__ bsum, int n)
{
    __shared__ int tmp[256];
    int i = blockIdx.x * 256 + threadIdx.x;
    int v = (i < n) ? in[i] : 0;
    tmp[threadIdx.x] = v;
    __syncthreads();
    for (int off = 1; off < 256; off <<= 1) {
        int t = (threadIdx.x >= off) ? tmp[threadIdx.x - off] : 0;
        __syncthreads();
        tmp[threadIdx.x] += t;
        __syncthreads();
    }
    if (i < n) part[i] = tmp[threadIdx.x] - v;
    if (threadIdx.x == 255) bsum[blockIdx.x] = tmp[255];
}

__global__ __launch_bounds__(1024) void scan2(int* __restrict__ bsum, int nb)
{
    __shared__ int tmp[1024];
    int tid = threadIdx.x;
    int v = (tid < nb) ? bsum[tid] : 0;
    tmp[tid] = v;
    __syncthreads();
    for (int off = 1; off < 1024; off <<= 1) {
        int t = (tid >= off) ? tmp[tid - off] : 0;
        __syncthreads();
        tmp[tid] += t;
        __syncthreads();
    }
    if (tid < nb) bsum[tid] = tmp[tid] - v;
}

__global__ __launch_bounds__(256) void scan3(
    const int* __restrict__ part, const int* __restrict__ bsum,
    int* __restrict__ rowptr, int* __restrict__ cursor, int n, int E)
{
    int i = blockIdx.x * 256 + threadIdx.x;
    if (i < n) {
        int v = part[i] + bsum[blockIdx.x];
        rowptr[i] = v;
        cursor[i] = v;
    }
    if (i == 0) rowptr[n] = E;
}

__global__ __launch_bounds__(256) void fill_csr(
    const int* __restrict__ ei, const int* __restrict__ et,
    int* __restrict__ cursor, int* __restrict__ spk, int E)
{
    int e = blockIdx.x * 256 + threadIdx.x;
    if (e < E) {
        int d = ei[E + e];
        int pos = atomicAdd(&cursor[d], 1);
        spk[pos] = ei[e] | (et[e] << 20);
    }
}

// ---------------------------------------------------------------------------
// conv_x: fp32 activations -> bf16, contiguous.
// ---------------------------------------------------------------------------
__global__ __launch_bounds__(256) void conv_x(
    const float* __restrict__ x, ushort* __restrict__ xb, int n4)
{
    int i = blockIdx.x * 256 + threadIdx.x;
    int stride = gridDim.x * 256;
    for (; i < n4; i += stride) {
        float4 v = ((const float4*)x)[i];
        ushort4 o;
        o.x = f2bf(v.x); o.y = f2bf(v.y); o.z = f2bf(v.z); o.w = f2bf(v.w);
        ((ushort4*)xb)[i] = o;
    }
}

// ---------------------------------------------------------------------------
// conv_wf: weights -> bf16 in MFMA-fragment order (round-9 win).
// ---------------------------------------------------------------------------
__global__ __launch_bounds__(256) void conv_wf(
    const float* __restrict__ W, const float* __restrict__ root,
    ushort* __restrict__ Wf)
{
    int i = blockIdx.x * 256 + threadIdx.x;
    if (i >= 128 * 1152) return;
    int f = i >> 9;
    int within = i & 511;
    int l = within >> 3;
    int j = within & 7;
    int rs = f >> 5;
    int kk = (f >> 3) & 3;
    int n  = f & 7;
    int col = (n << 4) | (l & 15);
    int kl  = kk * 32 + (l >> 4) * 8 + j;
    float v = (rs < 8) ? W[rs * 16384 + kl * 128 + col] : root[kl * 128 + col];
    Wf[i] = f2bf(v);
}

// ---------------------------------------------------------------------------
// FUSED gather + 9-source MFMA GEMM, v2 (round-13).
// Round-12 post-mortem: fusion regressed because 4 waves gathered 16 rows
// (4 serial CSR walks per wave); bank conflicts were negligible (~2.6us).
// Fix: block = 1024 thr = 16 waves -> ONE row per wave (round-11 parallelism),
// then K-split MFMA: waves 0-7 do n-block wid over rs0-3 + root(kk0-1);
// waves 8-15 same n-block over rs4-7 + root(kk2-3); partials reduced via
// 8KB LDS scratch. LDS 40KB, 2 blocks/CU (wave-limited) = full occupancy.
// ---------------------------------------------------------------------------
__global__ __launch_bounds__(1024) void fused_layer(
    const ushort* __restrict__ Xb, const int* __restrict__ rowptr,
    const int* __restrict__ spk, const int* __restrict__ cnt,
    const ushort* __restrict__ Wf, const float* __restrict__ bias,
    float* __restrict__ Ofp, ushort* __restrict__ Obf, int N, int relu)
{
    __shared__ ushort lds[8 * 16 * 128];   // 32 KB aggregated-A tile
    __shared__ f32x4 pscr[8 * 64];         // 8 KB partial accumulators

    int wid  = threadIdx.x >> 6;           // 0..15
    int lane = threadIdx.x & 63;
    int blk0 = blockIdx.x * 16;

    // ---------------- phase 1: gather ONE row per wave ----------------
    {
        int lrow16 = wid;
        int d = blk0 + lrow16;

        float2 a0 = {0.f, 0.f}, a1 = {0.f, 0.f}, a2 = {0.f, 0.f}, a3 = {0.f, 0.f};
        float2 a4 = {0.f, 0.f}, a5 = {0.f, 0.f}, a6 = {0.f, 0.f}, a7 = {0.f, 0.f};

        #define ROWLD(P) \
            (((const unsigned*)(Xb + (size_t)((P) & 0xFFFFF) * 128))[lane])
        #define CONSUME(P, U)                                               \
        {                                                                   \
            union { unsigned u; float f; } lo, hi;                          \
            lo.u = (U) << 16; hi.u = (U) & 0xFFFF0000u;                     \
            switch ((P) >> 20) {                                            \
                case 0: a0.x += lo.f; a0.y += hi.f; break;                  \
                case 1: a1.x += lo.f; a1.y += hi.f; break;                  \
                case 2: a2.x += lo.f; a2.y += hi.f; break;                  \
                case 3: a3.x += lo.f; a3.y += hi.f; break;                  \
                case 4: a4.x += lo.f; a4.y += hi.f; break;                  \
                case 5: a5.x += lo.f; a5.y += hi.f; break;                  \
                case 6: a6.x += lo.f; a6.y += hi.f; break;                  \
                default: a7.x += lo.f; a7.y += hi.f; break;                 \
            }                                                               \
        }

        if (d < N) {
            int beg = rowptr[d], end = rowptr[d + 1];
            int i = beg;
            for (; i + 4 <= end; i += 4) {
                int pk4 = spk[i + (lane & 3)];
                int p0 = __builtin_amdgcn_readlane(pk4, 0);
                int p1 = __builtin_amdgcn_readlane(pk4, 1);
                int p2 = __builtin_amdgcn_readlane(pk4, 2);
                int p3 = __builtin_amdgcn_readlane(pk4, 3);
                unsigned u0 = ROWLD(p0);
                unsigned u1 = ROWLD(p1);
                unsigned u2 = ROWLD(p2);
                unsigned u3 = ROWLD(p3);
                CONSUME(p0, u0);
                CONSUME(p1, u1);
                CONSUME(p2, u2);
                CONSUME(p3, u3);
            }
            for (; i < end; i++) {
                int p = __builtin_amdgcn_readfirstlane(spk[i]);
                unsigned u = ROWLD(p);
                CONSUME(p, u);
            }
        }
        #undef CONSUME
        #undef ROWLD

        // scale by 1/cnt, cvt bf16, swizzled LDS write (round-12 layout)
        unsigned swz = (unsigned)(lrow16 & 7) << 4;
        char* rowbase = (char*)lds + (lrow16 << 8);
        #define WR2(R, A)                                                   \
        {                                                                   \
            int c = (d < N) ? cnt[R * N + d] : 0;                           \
            float inv = (c > 0) ? 1.f / (float)c : 0.f;                     \
            unsigned pk = (unsigned)f2bf(A.x * inv)                         \
                        | ((unsigned)f2bf(A.y * inv) << 16);                \
            *(unsigned*)(rowbase + (R << 12) +                              \
                         ((((unsigned)lane << 2)) ^ swz)) = pk;             \
        }
        WR2(0, a0) WR2(1, a1) WR2(2, a2) WR2(3, a3)
        WR2(4, a4) WR2(5, a5) WR2(6, a6) WR2(7, a7)
        #undef WR2
    }
    __syncthreads();

    // ---------------- phase 2: K-split MFMA ----------------
    int lrow = lane & 15;
    int kgrp = lane >> 4;
    unsigned swzR = (unsigned)(lrow & 7) << 4;
    const bf16x8* Wf8 = (const bf16x8*)Wf;
    int n0    = wid & 7;                   // n-block (shared by wave pair)
    int upper = wid >> 3;                  // 0: rs0-3+root(kk0,1); 1: rs4-7+root(kk2,3)

    f32x4 acc = {0.f, 0.f, 0.f, 0.f};
    const char* abase = (const char*)lds + (lrow << 8);

    int rs0 = upper * 4;
    #pragma unroll 1
    for (int rs = rs0; rs < rs0 + 4; rs++) {
        const bf16x8* Bp = Wf8 + (size_t)rs * 2048 + (size_t)n0 * 64 + lane;
        #pragma unroll
        for (int kk = 0; kk < 4; kk++) {
            bf16x8 a = *(const bf16x8*)(abase + (rs << 12) +
                         (((unsigned)(kk * 64 + kgrp * 16)) ^ swzR));
            bf16x8 b = Bp[kk * 512];
            acc = __builtin_amdgcn_mfma_f32_16x16x32_bf16(a, b, acc, 0, 0, 0);
        }
    }
    {   // root source: upper half does kk 2,3; lower kk 0,1 (from global Xb)
        int arow = blk0 + lrow; if (arow >= N) arow = N - 1;
        const ushort* A = Xb + (size_t)arow * 128;
        const bf16x8* Bp = Wf8 + (size_t)8 * 2048 + (size_t)n0 * 64 + lane;
        #pragma unroll
        for (int k2 = 0; k2 < 2; k2++) {
            int kk = upper * 2 + k2;
            bf16x8 a = *(const bf16x8*)(A + kk * 32 + kgrp * 8);
            bf16x8 b = Bp[kk * 512];
            acc = __builtin_amdgcn_mfma_f32_16x16x32_bf16(a, b, acc, 0, 0, 0);
        }
    }

    // upper waves park partials; lower waves reduce + epilogue
    if (upper) pscr[(size_t)n0 * 64 + lane] = acc;
    __syncthreads();

    if (!upper) {
        f32x4 po = pscr[(size_t)n0 * 64 + lane];
        int row0 = blk0 + kgrp * 4;
        int col  = n0 * 16 + lrow;
        float bv = bias[col];
        #pragma unroll
        for (int r = 0; r < 4; r++) {
            int row = row0 + r;
            if (row < N) {
                float v = acc[r] + po[r] + bv;
                if (relu) v = fmaxf(v, 0.f);
                if (Ofp) Ofp[(size_t)row * 128 + col] = v;
                if (Obf) Obf[(size_t)row * 128 + col] = f2bf(v);
            }
        }
    }
}

// ---------------------------------------------------------------------------
// out[n][c] = sum_k emb[n][k] * Wc[k*16+c] + bc[c];   16 nodes / block
// ---------------------------------------------------------------------------
__global__ __launch_bounds__(256) void classifier(
    const float* __restrict__ emb, const float* __restrict__ Wc,
    const float* __restrict__ bc, float* __restrict__ out, int N)
{
    int t = threadIdx.x;
    int c = t & 15;
    int n = blockIdx.x * 16 + (t >> 4);
    if (n >= N) return;
    const float* e = emb + (size_t)n * 128;
    float acc = bc[c];
    #pragma unroll 8
    for (int k = 0; k < 128; k++) acc += e[k] * Wc[k * 16 + c];
    out[(size_t)n * 16 + c] = acc;
}

static inline size_t align256(size_t x) { return (x + 255) & ~(size_t)255; }

extern "C" void kernel_launch(void* const* d_in, const int* in_sizes, int n_in,
                              void* d_out, int out_size, void* d_ws, size_t ws_size,
                              hipStream_t stream)
{
    const float* x     = (const float*)d_in[0];
    const int*   ei    = (const int*)d_in[1];
    const int*   et    = (const int*)d_in[2];
    const float* W1    = (const float*)d_in[3];
    const float* root1 = (const float*)d_in[4];
    const float* b1    = (const float*)d_in[5];
    const float* W2    = (const float*)d_in[6];
    const float* root2 = (const float*)d_in[7];
    const float* b2    = (const float*)d_in[8];
    const float* Wc    = (const float*)d_in[9];
    const float* bc    = (const float*)d_in[10];

    const int N = in_sizes[0] / 128;
    const int E = in_sizes[2];
    const int C = in_sizes[10];   // 16

    float* out = (float*)d_out;                 // [N,16]
    float* emb = out + (size_t)N * C;           // [N,128] fp32 (2nd output)

    // ws: cnt | rowptr | cursor | part | bsum | spk | xb | hb | Wf1 | Wf2
    size_t cntB  = align256((size_t)NREL * N * sizeof(int));
    size_t rpB   = align256((size_t)(N + 1) * sizeof(int));
    size_t curB  = align256((size_t)N * sizeof(int));
    size_t bsB   = align256((size_t)1024 * sizeof(int));
    size_t spkB  = align256((size_t)E * sizeof(int));
    size_t xbB   = align256((size_t)N * 128 * sizeof(ushort));
    size_t wtB   = align256((size_t)128 * 1152 * sizeof(ushort));

    char* p = (char*)d_ws;
    int*    cnt    = (int*)p;      p += cntB;
    int*    rowptr = (int*)p;      p += rpB;
    int*    cursor = (int*)p;      p += curB;
    int*    part   = (int*)p;      p += curB;
    int*    bsum   = (int*)p;      p += bsB;
    int*    spk    = (int*)p;      p += spkB;
    ushort* xb     = (ushort*)p;   p += xbB;
    ushort* hb     = (ushort*)p;   p += xbB;
    ushort* Wf1    = (ushort*)p;   p += wtB;
    ushort* Wf2    = (ushort*)p;

    dim3 blk(256);
    int gE    = (E + 255) / 256;
    int gN    = (N + 255) / 256;     // <=1024 for scan2
    int gFus  = (N + 15) / 16;       // 3125 blocks of 1024 threads
    int gCls  = (N + 15) / 16;
    int gWt   = (128 * 1152 + 255) / 256;
    long long cnt4 = (long long)NREL * N / 4;
    int gZ = (int)((cnt4 + 255) / 256); if (gZ > 2048) gZ = 2048;
    int nx4 = N * 32;
    int gCx = (nx4 + 255) / 256; if (gCx > 2048) gCx = 2048;

    // ---- CSR build (shared by both layers) ----
    zero16<<<gZ, blk, 0, stream>>>((float4*)cnt, (int)cnt4);
    count_edges<<<gE, blk, 0, stream>>>(ei, et, cnt, E, N);
    dst_counts<<<gN, blk, 0, stream>>>(cnt, cursor, N);
    scan1<<<gN, blk, 0, stream>>>(cursor, part, bsum, N);
    scan2<<<1, 1024, 0, stream>>>(bsum, gN);
    scan3<<<gN, blk, 0, stream>>>(part, bsum, rowptr, cursor, N, E);
    fill_csr<<<gE, blk, 0, stream>>>(ei, et, cursor, spk, E);

    // ---- bf16 conversions ----
    conv_x<<<gCx, blk, 0, stream>>>(x, xb, nx4);
    conv_wf<<<gWt, blk, 0, stream>>>(W1, root1, Wf1);
    conv_wf<<<gWt, blk, 0, stream>>>(W2, root2, Wf2);

    // ---- layer 1: fused gather+GEMM -> hb (bf16, relu) ----
    fused_layer<<<gFus, dim3(1024), 0, stream>>>(xb, rowptr, spk, cnt, Wf1, b1,
                                                 nullptr, hb, N, 1);

    // ---- layer 2: fused gather+GEMM -> emb (fp32) ----
    fused_layer<<<gFus, dim3(1024), 0, stream>>>(hb, rowptr, spk, cnt, Wf2, b2,
                                                 emb, nullptr, N, 0);

    // ---- classifier ----
    classifier<<<gCls, blk, 0, stream>>>(emb, Wc, bc, out, N);
}

// Round 14
// 313.569 us; speedup vs baseline: 1.2224x; 1.0381x over previous
//
#include <hip/hip_runtime.h>

#define NREL 8

typedef __attribute__((ext_vector_type(8))) short bf16x8;
typedef __attribute__((ext_vector_type(4))) float f32x4;

__device__ inline ushort f2bf(float f)
{
    union { float f; unsigned u; } v; v.f = f;
    unsigned r = v.u + 0x7FFF + ((v.u >> 16) & 1);   // RNE
    return (ushort)(r >> 16);
}

// ---------------------------------------------------------------------------
// zero16: graph-capturable memset replacement (round-2 lesson).
// ---------------------------------------------------------------------------
__global__ __launch_bounds__(256) void zero16(float4* __restrict__ p, int n4)
{
    int i = blockIdx.x * 256 + threadIdx.x;
    int stride = gridDim.x * 256;
    for (; i < n4; i += stride) p[i] = make_float4(0.f, 0.f, 0.f, 0.f);
}

// ---------------------------------------------------------------------------
// CSR build: count -> dst totals -> 3-kernel multi-block scan -> fill.
// ---------------------------------------------------------------------------
__global__ __launch_bounds__(256) void count_edges(
    const int* __restrict__ ei, const int* __restrict__ et,
    int* __restrict__ cnt, int E, int N)
{
    int e = blockIdx.x * 256 + threadIdx.x;
    if (e < E) {
        int d = ei[E + e];
        int r = et[e];
        atomicAdd(&cnt[r * N + d], 1);
    }
}

__global__ __launch_bounds__(256) void dst_counts(
    const int* __restrict__ cnt, int* __restrict__ dcnt, int N)
{
    int d = blockIdx.x * 256 + threadIdx.x;
    if (d < N) {
        int s = 0;
        #pragma unroll
        for (int r = 0; r < NREL; r++) s += cnt[r * N + d];
        dcnt[d] = s;
    }
}

__global__ __launch_bounds__(256) void scan1(
    const int* __restrict__ in, int* __restrict__ part,
    int* __restrict__ bsum, int n)
{
    __shared__ int tmp[256];
    int i = blockIdx.x * 256 + threadIdx.x;
    int v = (i < n) ? in[i] : 0;
    tmp[threadIdx.x] = v;
    __syncthreads();
    for (int off = 1; off < 256; off <<= 1) {
        int t = (threadIdx.x >= off) ? tmp[threadIdx.x - off] : 0;
        __syncthreads();
        tmp[threadIdx.x] += t;
        __syncthreads();
    }
    if (i < n) part[i] = tmp[threadIdx.x] - v;
    if (threadIdx.x == 255) bsum[blockIdx.x] = tmp[255];
}

__global__ __launch_bounds__(1024) void scan2(int* __restrict__ bsum, int nb)
{
    __shared__ int tmp[1024];
    int tid = threadIdx.x;
    int v = (tid < nb) ? bsum[tid] : 0;
    tmp[tid] = v;
    __syncthreads();
    for (int off = 1; off < 1024; off <<= 1) {
        int t = (tid >= off) ? tmp[tid - off] : 0;
        __syncthreads();
        tmp[tid] += t;
        __syncthreads();
    }
    if (tid < nb) bsum[tid] = tmp[tid] - v;
}

__global__ __launch_bounds__(256) void scan3(
    const int* __restrict__ part, const int* __restrict__ bsum,
    int* __restrict__ rowptr, int* __restrict__ cursor, int n, int E)
{
    int i = blockIdx.x * 256 + threadIdx.x;
    if (i < n) {
        int v = part[i] + bsum[blockIdx.x];
        rowptr[i] = v;
        cursor[i] = v;
    }
    if (i == 0) rowptr[n] = E;
}

__global__ __launch_bounds__(256) void fill_csr(
    const int* __restrict__ ei, const int* __restrict__ et,
    int* __restrict__ cursor, int* __restrict__ spk, int E)
{
    int e = blockIdx.x * 256 + threadIdx.x;
    if (e < E) {
        int d = ei[E + e];
        int pos = atomicAdd(&cursor[d], 1);
        spk[pos] = ei[e] | (et[e] << 20);
    }
}

// ---------------------------------------------------------------------------
// conv_x: fp32 activations -> bf16, contiguous.
// ---------------------------------------------------------------------------
__global__ __launch_bounds__(256) void conv_x(
    const float* __restrict__ x, ushort* __restrict__ xb, int n4)
{
    int i = blockIdx.x * 256 + threadIdx.x;
    int stride = gridDim.x * 256;
    for (; i < n4; i += stride) {
        float4 v = ((const float4*)x)[i];
        ushort4 o;
        o.x = f2bf(v.x); o.y = f2bf(v.y); o.z = f2bf(v.z); o.w = f2bf(v.w);
        ((ushort4*)xb)[i] = o;
    }
}

// ---------------------------------------------------------------------------
// conv_wf: weights -> bf16 in MFMA-fragment order (round-9 win).
// ---------------------------------------------------------------------------
__global__ __launch_bounds__(256) void conv_wf(
    const float* __restrict__ W, const float* __restrict__ root,
    ushort* __restrict__ Wf)
{
    int i = blockIdx.x * 256 + threadIdx.x;
    if (i >= 128 * 1152) return;
    int f = i >> 9;
    int within = i & 511;
    int l = within >> 3;
    int j = within & 7;
    int rs = f >> 5;
    int kk = (f >> 3) & 3;
    int n  = f & 7;
    int col = (n << 4) | (l & 15);
    int kl  = kk * 32 + (l >> 4) * 8 + j;
    float v = (rs < 8) ? W[rs * 16384 + kl * 128 + col] : root[kl * 128 + col];
    Wf[i] = f2bf(v);
}

// ---------------------------------------------------------------------------
// FUSED gather + 9-source MFMA GEMM, v3 (round-14).
// Round-13 post-mortem: VGPR_Count=24 -> compiler register-minimized and
// SERIALIZED the load chains (round-8 pathology). Fix is structural ILP:
//  - gather: 8-deep named u0..u7 batch (one spk load covers 8 edges)
//  - MFMA: per rs, named a0..a3 (ds_read) + b0..b3 (global) loaded before
//    the 4 chained MFMAs.
// Live set ~56-64 VGPR, deliberately <=64 to keep 2 blocks/CU (32 waves).
// ---------------------------------------------------------------------------
__global__ __launch_bounds__(1024) void fused_layer(
    const ushort* __restrict__ Xb, const int* __restrict__ rowptr,
    const int* __restrict__ spk, const int* __restrict__ cnt,
    const ushort* __restrict__ Wf, const float* __restrict__ bias,
    float* __restrict__ Ofp, ushort* __restrict__ Obf, int N, int relu)
{
    __shared__ ushort lds[8 * 16 * 128];   // 32 KB aggregated-A tile
    __shared__ f32x4 pscr[8 * 64];         // 8 KB partial accumulators

    int wid  = threadIdx.x >> 6;           // 0..15
    int lane = threadIdx.x & 63;
    int blk0 = blockIdx.x * 16;

    // ---------------- phase 1: gather ONE row per wave ----------------
    {
        int lrow16 = wid;
        int d = blk0 + lrow16;

        float2 a0 = {0.f, 0.f}, a1 = {0.f, 0.f}, a2 = {0.f, 0.f}, a3 = {0.f, 0.f};
        float2 a4 = {0.f, 0.f}, a5 = {0.f, 0.f}, a6 = {0.f, 0.f}, a7 = {0.f, 0.f};

        #define ROWLD(P) \
            (((const unsigned*)(Xb + (size_t)((P) & 0xFFFFF) * 128))[lane])
        #define CONSUME(P, U)                                               \
        {                                                                   \
            union { unsigned u; float f; } lo, hi;                          \
            lo.u = (U) << 16; hi.u = (U) & 0xFFFF0000u;                     \
            switch ((P) >> 20) {                                            \
                case 0: a0.x += lo.f; a0.y += hi.f; break;                  \
                case 1: a1.x += lo.f; a1.y += hi.f; break;                  \
                case 2: a2.x += lo.f; a2.y += hi.f; break;                  \
                case 3: a3.x += lo.f; a3.y += hi.f; break;                  \
                case 4: a4.x += lo.f; a4.y += hi.f; break;                  \
                case 5: a5.x += lo.f; a5.y += hi.f; break;                  \
                case 6: a6.x += lo.f; a6.y += hi.f; break;                  \
                default: a7.x += lo.f; a7.y += hi.f; break;                 \
            }                                                               \
        }

        if (d < N) {
            int beg = rowptr[d], end = rowptr[d + 1];
            int i = beg;
            // 8-deep MLP: one spk load covers 8 edges; 8 named row loads
            for (; i + 8 <= end; i += 8) {
                int pk8 = spk[i + (lane & 7)];
                int p0 = __builtin_amdgcn_readlane(pk8, 0);
                int p1 = __builtin_amdgcn_readlane(pk8, 1);
                int p2 = __builtin_amdgcn_readlane(pk8, 2);
                int p3 = __builtin_amdgcn_readlane(pk8, 3);
                int p4 = __builtin_amdgcn_readlane(pk8, 4);
                int p5 = __builtin_amdgcn_readlane(pk8, 5);
                int p6 = __builtin_amdgcn_readlane(pk8, 6);
                int p7 = __builtin_amdgcn_readlane(pk8, 7);
                unsigned u0 = ROWLD(p0);
                unsigned u1 = ROWLD(p1);
                unsigned u2 = ROWLD(p2);
                unsigned u3 = ROWLD(p3);
                unsigned u4 = ROWLD(p4);
                unsigned u5 = ROWLD(p5);
                unsigned u6 = ROWLD(p6);
                unsigned u7 = ROWLD(p7);
                CONSUME(p0, u0);
                CONSUME(p1, u1);
                CONSUME(p2, u2);
                CONSUME(p3, u3);
                CONSUME(p4, u4);
                CONSUME(p5, u5);
                CONSUME(p6, u6);
                CONSUME(p7, u7);
            }
            for (; i + 4 <= end; i += 4) {
                int pk4 = spk[i + (lane & 3)];
                int p0 = __builtin_amdgcn_readlane(pk4, 0);
                int p1 = __builtin_amdgcn_readlane(pk4, 1);
                int p2 = __builtin_amdgcn_readlane(pk4, 2);
                int p3 = __builtin_amdgcn_readlane(pk4, 3);
                unsigned u0 = ROWLD(p0);
                unsigned u1 = ROWLD(p1);
                unsigned u2 = ROWLD(p2);
                unsigned u3 = ROWLD(p3);
                CONSUME(p0, u0);
                CONSUME(p1, u1);
                CONSUME(p2, u2);
                CONSUME(p3, u3);
            }
            for (; i < end; i++) {
                int p = __builtin_amdgcn_readfirstlane(spk[i]);
                unsigned u = ROWLD(p);
                CONSUME(p, u);
            }
        }
        #undef CONSUME
        #undef ROWLD

        // scale by 1/cnt, cvt bf16, swizzled LDS write
        unsigned swz = (unsigned)(lrow16 & 7) << 4;
        char* rowbase = (char*)lds + (lrow16 << 8);
        #define WR2(R, A)                                                   \
        {                                                                   \
            int c = (d < N) ? cnt[R * N + d] : 0;                           \
            float inv = (c > 0) ? 1.f / (float)c : 0.f;                     \
            unsigned pk = (unsigned)f2bf(A.x * inv)                         \
                        | ((unsigned)f2bf(A.y * inv) << 16);                \
            *(unsigned*)(rowbase + (R << 12) +                              \
                         ((((unsigned)lane << 2)) ^ swz)) = pk;             \
        }
        WR2(0, a0) WR2(1, a1) WR2(2, a2) WR2(3, a3)
        WR2(4, a4) WR2(5, a5) WR2(6, a6) WR2(7, a7)
        #undef WR2
    }
    __syncthreads();

    // ---------------- phase 2: K-split MFMA, named-batch loads ----------------
    int lrow = lane & 15;
    int kgrp = lane >> 4;
    unsigned swzR = (unsigned)(lrow & 7) << 4;
    const bf16x8* Wf8 = (const bf16x8*)Wf;
    int n0    = wid & 7;                   // n-block (shared by wave pair)
    int upper = wid >> 3;                  // 0: rs0-3+root(kk0,1); 1: rs4-7+root(kk2,3)

    f32x4 acc = {0.f, 0.f, 0.f, 0.f};
    const char* abase = (const char*)lds + (lrow << 8);

    int rs0 = upper * 4;
    #pragma unroll 1
    for (int rs = rs0; rs < rs0 + 4; rs++) {
        const bf16x8* Bp = Wf8 + (size_t)rs * 2048 + (size_t)n0 * 64 + lane;
        const char* ab = abase + (rs << 12);
        // named batch: 4 ds_reads + 4 global loads in flight before MFMAs
        bf16x8 a0 = *(const bf16x8*)(ab + ((unsigned)(0 * 64 + kgrp * 16) ^ swzR));
        bf16x8 a1 = *(const bf16x8*)(ab + ((unsigned)(1 * 64 + kgrp * 16) ^ swzR));
        bf16x8 a2 = *(const bf16x8*)(ab + ((unsigned)(2 * 64 + kgrp * 16) ^ swzR));
        bf16x8 a3 = *(const bf16x8*)(ab + ((unsigned)(3 * 64 + kgrp * 16) ^ swzR));
        bf16x8 b0 = Bp[0];
        bf16x8 b1 = Bp[512];
        bf16x8 b2 = Bp[1024];
        bf16x8 b3 = Bp[1536];
        acc = __builtin_amdgcn_mfma_f32_16x16x32_bf16(a0, b0, acc, 0, 0, 0);
        acc = __builtin_amdgcn_mfma_f32_16x16x32_bf16(a1, b1, acc, 0, 0, 0);
        acc = __builtin_amdgcn_mfma_f32_16x16x32_bf16(a2, b2, acc, 0, 0, 0);
        acc = __builtin_amdgcn_mfma_f32_16x16x32_bf16(a3, b3, acc, 0, 0, 0);
    }
    {   // root source: upper half does kk 2,3; lower kk 0,1 (from global Xb)
        int arow = blk0 + lrow; if (arow >= N) arow = N - 1;
        const ushort* A = Xb + (size_t)arow * 128;
        const bf16x8* Bp = Wf8 + (size_t)8 * 2048 + (size_t)n0 * 64 + lane;
        int kkb = upper * 2;
        bf16x8 a0 = *(const bf16x8*)(A + (kkb + 0) * 32 + kgrp * 8);
        bf16x8 a1 = *(const bf16x8*)(A + (kkb + 1) * 32 + kgrp * 8);
        bf16x8 b0 = Bp[(kkb + 0) * 512];
        bf16x8 b1 = Bp[(kkb + 1) * 512];
        acc = __builtin_amdgcn_mfma_f32_16x16x32_bf16(a0, b0, acc, 0, 0, 0);
        acc = __builtin_amdgcn_mfma_f32_16x16x32_bf16(a1, b1, acc, 0, 0, 0);
    }

    // upper waves park partials; lower waves reduce + epilogue
    if (upper) pscr[(size_t)n0 * 64 + lane] = acc;
    __syncthreads();

    if (!upper) {
        f32x4 po = pscr[(size_t)n0 * 64 + lane];
        int row0 = blk0 + kgrp * 4;
        int col  = n0 * 16 + lrow;
        float bv = bias[col];
        #pragma unroll
        for (int r = 0; r < 4; r++) {
            int row = row0 + r;
            if (row < N) {
                float v = acc[r] + po[r] + bv;
                if (relu) v = fmaxf(v, 0.f);
                if (Ofp) Ofp[(size_t)row * 128 + col] = v;
                if (Obf) Obf[(size_t)row * 128 + col] = f2bf(v);
            }
        }
    }
}

// ---------------------------------------------------------------------------
// out[n][c] = sum_k emb[n][k] * Wc[k*16+c] + bc[c];   16 nodes / block
// ---------------------------------------------------------------------------
__global__ __launch_bounds__(256) void classifier(
    const float* __restrict__ emb, const float* __restrict__ Wc,
    const float* __restrict__ bc, float* __restrict__ out, int N)
{
    int t = threadIdx.x;
    int c = t & 15;
    int n = blockIdx.x * 16 + (t >> 4);
    if (n >= N) return;
    const float* e = emb + (size_t)n * 128;
    float acc = bc[c];
    #pragma unroll 8
    for (int k = 0; k < 128; k++) acc += e[k] * Wc[k * 16 + c];
    out[(size_t)n * 16 + c] = acc;
}

static inline size_t align256(size_t x) { return (x + 255) & ~(size_t)255; }

extern "C" void kernel_launch(void* const* d_in, const int* in_sizes, int n_in,
                              void* d_out, int out_size, void* d_ws, size_t ws_size,
                              hipStream_t stream)
{
    const float* x     = (const float*)d_in[0];
    const int*   ei    = (const int*)d_in[1];
    const int*   et    = (const int*)d_in[2];
    const float* W1    = (const float*)d_in[3];
    const float* root1 = (const float*)d_in[4];
    const float* b1    = (const float*)d_in[5];
    const float* W2    = (const float*)d_in[6];
    const float* root2 = (const float*)d_in[7];
    const float* b2    = (const float*)d_in[8];
    const float* Wc    = (const float*)d_in[9];
    const float* bc    = (const float*)d_in[10];

    const int N = in_sizes[0] / 128;
    const int E = in_sizes[2];
    const int C = in_sizes[10];   // 16

    float* out = (float*)d_out;                 // [N,16]
    float* emb = out + (size_t)N * C;           // [N,128] fp32 (2nd output)

    // ws: cnt | rowptr | cursor | part | bsum | spk | xb | hb | Wf1 | Wf2
    size_t cntB  = align256((size_t)NREL * N * sizeof(int));
    size_t rpB   = align256((size_t)(N + 1) * sizeof(int));
    size_t curB  = align256((size_t)N * sizeof(int));
    size_t bsB   = align256((size_t)1024 * sizeof(int));
    size_t spkB  = align256((size_t)E * sizeof(int));
    size_t xbB   = align256((size_t)N * 128 * sizeof(ushort));
    size_t wtB   = align256((size_t)128 * 1152 * sizeof(ushort));

    char* p = (char*)d_ws;
    int*    cnt    = (int*)p;      p += cntB;
    int*    rowptr = (int*)p;      p += rpB;
    int*    cursor = (int*)p;      p += curB;
    int*    part   = (int*)p;      p += curB;
    int*    bsum   = (int*)p;      p += bsB;
    int*    spk    = (int*)p;      p += spkB;
    ushort* xb     = (ushort*)p;   p += xbB;
    ushort* hb     = (ushort*)p;   p += xbB;
    ushort* Wf1    = (ushort*)p;   p += wtB;
    ushort* Wf2    = (ushort*)p;

    dim3 blk(256);
    int gE    = (E + 255) / 256;
    int gN    = (N + 255) / 256;     // <=1024 for scan2
    int gFus  = (N + 15) / 16;       // 3125 blocks of 1024 threads
    int gCls  = (N + 15) / 16;
    int gWt   = (128 * 1152 + 255) / 256;
    long long cnt4 = (long long)NREL * N / 4;
    int gZ = (int)((cnt4 + 255) / 256); if (gZ > 2048) gZ = 2048;
    int nx4 = N * 32;
    int gCx = (nx4 + 255) / 256; if (gCx > 2048) gCx = 2048;

    // ---- CSR build (shared by both layers) ----
    zero16<<<gZ, blk, 0, stream>>>((float4*)cnt, (int)cnt4);
    count_edges<<<gE, blk, 0, stream>>>(ei, et, cnt, E, N);
    dst_counts<<<gN, blk, 0, stream>>>(cnt, cursor, N);
    scan1<<<gN, blk, 0, stream>>>(cursor, part, bsum, N);
    scan2<<<1, 1024, 0, stream>>>(bsum, gN);
    scan3<<<gN, blk, 0, stream>>>(part, bsum, rowptr, cursor, N, E);
    fill_csr<<<gE, blk, 0, stream>>>(ei, et, cursor, spk, E);

    // ---- bf16 conversions ----
    conv_x<<<gCx, blk, 0, stream>>>(x, xb, nx4);
    conv_wf<<<gWt, blk, 0, stream>>>(W1, root1, Wf1);
    conv_wf<<<gWt, blk, 0, stream>>>(W2, root2, Wf2);

    // ---- layer 1: fused gather+GEMM -> hb (bf16, relu) ----
    fused_layer<<<gFus, dim3(1024), 0, stream>>>(xb, rowptr, spk, cnt, Wf1, b1,
                                                 nullptr, hb, N, 1);

    // ---- layer 2: fused gather+GEMM -> emb (fp32) ----
    fused_layer<<<gFus, dim3(1024), 0, stream>>>(hb, rowptr, spk, cnt, Wf2, b2,
                                                 emb, nullptr, N, 0);

    // ---- classifier ----
    classifier<<<gCls, blk, 0, stream>>>(emb, Wc, bc, out, N);
}

// Round 15
// 271.820 us; speedup vs baseline: 1.4101x; 1.1536x over previous
//
#include <hip/hip_runtime.h>

#define NREL 8

typedef __attribute__((ext_vector_type(8))) short bf16x8;
typedef __attribute__((ext_vector_type(4))) float f32x4;

__device__ inline ushort f2bf(float f)
{
    union { float f; unsigned u; } v; v.f = f;
    unsigned r = v.u + 0x7FFF + ((v.u >> 16) & 1);   // RNE
    return (ushort)(r >> 16);
}

// packed RNE f32x2 -> bf16x2 in one instruction (same rounding as f2bf)
__device__ inline unsigned cvtpk(float lo, float hi)
{
    unsigned r;
    asm("v_cvt_pk_bf16_f32 %0, %1, %2" : "=v"(r) : "v"(lo), "v"(hi));
    return r;
}

// ---------------------------------------------------------------------------
// zero16: graph-capturable memset replacement (round-2 lesson).
// ---------------------------------------------------------------------------
__global__ __launch_bounds__(256) void zero16(float4* __restrict__ p, int n4)
{
    int i = blockIdx.x * 256 + threadIdx.x;
    int stride = gridDim.x * 256;
    for (; i < n4; i += stride) p[i] = make_float4(0.f, 0.f, 0.f, 0.f);
}

// ---------------------------------------------------------------------------
// CSR build: count -> fused{totals+inv+scan} -> scan2 -> scan3 -> fill.
// ---------------------------------------------------------------------------
__global__ __launch_bounds__(256) void count_edges(
    const int* __restrict__ ei, const int* __restrict__ et,
    int* __restrict__ cnt, int E, int N)
{
    int e = blockIdx.x * 256 + threadIdx.x;
    if (e < E) {
        int d = ei[E + e];
        int r = et[e];
        atomicAdd(&cnt[r * N + d], 1);
    }
}

// fused: per-dst total, per-(d,r) reciprocal table, block-level exclusive scan
__global__ __launch_bounds__(256) void scan1f(
    const int* __restrict__ cnt, float* __restrict__ invc8,
    int* __restrict__ part, int* __restrict__ bsum, int N)
{
    __shared__ int tmp[256];
    int d = blockIdx.x * 256 + threadIdx.x;
    int s = 0;
    if (d < N) {
        #pragma unroll
        for (int r = 0; r < NREL; r++) {
            int c = cnt[r * N + d];
            s += c;
            invc8[(size_t)d * 8 + r] = (c > 0) ? 1.f / (float)c : 0.f;
        }
    }
    int v = s;
    tmp[threadIdx.x] = v;
    __syncthreads();
    for (int off = 1; off < 256; off <<= 1) {
        int t = (threadIdx.x >= off) ? tmp[threadIdx.x - off] : 0;
        __syncthreads();
        tmp[threadIdx.x] += t;
        __syncthreads();
    }
    if (d < N) part[d] = tmp[threadIdx.x] - v;
    if (threadIdx.x == 255) bsum[blockIdx.x] = tmp[255];
}

__global__ __launch_bounds__(1024) void scan2(int* __restrict__ bsum, int nb)
{
    __shared__ int tmp[1024];
    int tid = threadIdx.x;
    int v = (tid < nb) ? bsum[tid] : 0;
    tmp[tid] = v;
    __syncthreads();
    for (int off = 1; off < 1024; off <<= 1) {
        int t = (tid >= off) ? tmp[tid - off] : 0;
        __syncthreads();
        tmp[tid] += t;
        __syncthreads();
    }
    if (tid < nb) bsum[tid] = tmp[tid] - v;
}

__global__ __launch_bounds__(256) void scan3(
    const int* __restrict__ part, const int* __restrict__ bsum,
    int* __restrict__ rowptr, int* __restrict__ cursor, int n, int E)
{
    int i = blockIdx.x * 256 + threadIdx.x;
    if (i < n) {
        int v = part[i] + bsum[blockIdx.x];
        rowptr[i] = v;
        cursor[i] = v;
    }
    if (i == 0) rowptr[n] = E;
}

// spk packs (src << 8) | rel  ->  row byte-offset = pk & 0xFFFFFF00
__global__ __launch_bounds__(256) void fill_csr(
    const int* __restrict__ ei, const int* __restrict__ et,
    int* __restrict__ cursor, int* __restrict__ spk, int E)
{
    int e = blockIdx.x * 256 + threadIdx.x;
    if (e < E) {
        int d = ei[E + e];
        int pos = atomicAdd(&cursor[d], 1);
        spk[pos] = (ei[e] << 8) | et[e];
    }
}

// ---------------------------------------------------------------------------
// conv_x: fp32 activations -> bf16, contiguous.
// ---------------------------------------------------------------------------
__global__ __launch_bounds__(256) void conv_x(
    const float* __restrict__ x, ushort* __restrict__ xb, int n4)
{
    int i = blockIdx.x * 256 + threadIdx.x;
    int stride = gridDim.x * 256;
    for (; i < n4; i += stride) {
        float4 v = ((const float4*)x)[i];
        ushort4 o;
        o.x = f2bf(v.x); o.y = f2bf(v.y); o.z = f2bf(v.z); o.w = f2bf(v.w);
        ((ushort4*)xb)[i] = o;
    }
}

// ---------------------------------------------------------------------------
// conv_wfB: both layers' weights -> bf16 MFMA-fragment order; y picks layer.
// ---------------------------------------------------------------------------
__global__ __launch_bounds__(256) void conv_wfB(
    const float* __restrict__ W1, const float* __restrict__ root1,
    ushort* __restrict__ Wf1,
    const float* __restrict__ W2, const float* __restrict__ root2,
    ushort* __restrict__ Wf2)
{
    const float* W    = blockIdx.y ? W2 : W1;
    const float* root = blockIdx.y ? root2 : root1;
    ushort* Wf        = blockIdx.y ? Wf2 : Wf1;
    int i = blockIdx.x * 256 + threadIdx.x;
    if (i >= 128 * 1152) return;
    int f = i >> 9;
    int within = i & 511;
    int l = within >> 3;
    int j = within & 7;
    int rs = f >> 5;
    int kk = (f >> 3) & 3;
    int n  = f & 7;
    int col = (n << 4) | (l & 15);
    int kl  = kk * 32 + (l >> 4) * 8 + j;
    float v = (rs < 8) ? W[rs * 16384 + kl * 128 + col] : root[kl * 128 + col];
    Wf[i] = f2bf(v);
}

// ---------------------------------------------------------------------------
// FUSED gather + 9-source MFMA GEMM + (layer-2) classifier, v4 (round-15).
// Round-14 post-mortem: VALUBusy 47% = VALU-instruction-count bound, not
// latency (76% occupancy hides it; m219 lesson). Diet applied:
//  - spk = (src<<8)|rel: addr = SALU mask + 1 v_or per edge (was ~5 ops 64b)
//  - invc8 table: kills 8 full-precision divides per row
//  - v_cvt_pk_bf16_f32: 1 instr per bf16 pair in WR2 (was ~9)
//  - classifier fused into layer-2 epilogue via LDS (kills launch + 25.6MB
//    emb re-read)
// ---------------------------------------------------------------------------
__global__ __launch_bounds__(1024) void fused_layer(
    const ushort* __restrict__ Xb, const int* __restrict__ rowptr,
    const int* __restrict__ spk, const float* __restrict__ invc8,
    const ushort* __restrict__ Wf, const float* __restrict__ bias,
    float* __restrict__ Ofp, ushort* __restrict__ Obf,
    const float* __restrict__ Wc, const float* __restrict__ bc,
    float* __restrict__ outC, int N, int relu)
{
    __shared__ ushort lds[8 * 16 * 128];   // 32 KB aggregated-A tile
    __shared__ f32x4 pscr[8 * 64];         // 8 KB partial accumulators
    __shared__ float wcs[128][16];         // 8 KB classifier weights
    __shared__ float bcs[16];
    __shared__ float embt[16][128];        // 8 KB emb tile for classifier

    int wid  = threadIdx.x >> 6;           // 0..15
    int lane = threadIdx.x & 63;
    int blk0 = blockIdx.x * 16;
    int lane4 = lane << 2;

    // stage classifier weights (layer-2 only; uniform branch)
    if (outC) {
        for (int i = threadIdx.x; i < 2048; i += 1024)
            wcs[i >> 4][i & 15] = Wc[i];
        if (threadIdx.x < 16) bcs[threadIdx.x] = bc[threadIdx.x];
    }

    // ---------------- phase 1: gather ONE row per wave ----------------
    {
        int lrow16 = wid;
        int d = blk0 + lrow16;

        float2 a0 = {0.f, 0.f}, a1 = {0.f, 0.f}, a2 = {0.f, 0.f}, a3 = {0.f, 0.f};
        float2 a4 = {0.f, 0.f}, a5 = {0.f, 0.f}, a6 = {0.f, 0.f}, a7 = {0.f, 0.f};

        // SP = scalar (pk & 0xFFFFFF00) = row byte offset; 1 v_or per edge
        #define ROWLD(SP) \
            (*(const unsigned*)((const char*)Xb + (unsigned)((SP) | lane4)))
        #define CONSUME(P, U)                                               \
        {                                                                   \
            union { unsigned u; float f; } lo, hi;                          \
            lo.u = (U) << 16; hi.u = (U) & 0xFFFF0000u;                     \
            switch ((P) & 0xFF) {                                           \
                case 0: a0.x += lo.f; a0.y += hi.f; break;                  \
                case 1: a1.x += lo.f; a1.y += hi.f; break;                  \
                case 2: a2.x += lo.f; a2.y += hi.f; break;                  \
                case 3: a3.x += lo.f; a3.y += hi.f; break;                  \
                case 4: a4.x += lo.f; a4.y += hi.f; break;                  \
                case 5: a5.x += lo.f; a5.y += hi.f; break;                  \
                case 6: a6.x += lo.f; a6.y += hi.f; break;                  \
                default: a7.x += lo.f; a7.y += hi.f; break;                 \
            }                                                               \
        }

        if (d < N) {
            int beg = rowptr[d], end = rowptr[d + 1];
            int i = beg;
            for (; i + 8 <= end; i += 8) {
                int pk8 = spk[i + (lane & 7)];
                int p0 = __builtin_amdgcn_readlane(pk8, 0);
                int p1 = __builtin_amdgcn_readlane(pk8, 1);
                int p2 = __builtin_amdgcn_readlane(pk8, 2);
                int p3 = __builtin_amdgcn_readlane(pk8, 3);
                int p4 = __builtin_amdgcn_readlane(pk8, 4);
                int p5 = __builtin_amdgcn_readlane(pk8, 5);
                int p6 = __builtin_amdgcn_readlane(pk8, 6);
                int p7 = __builtin_amdgcn_readlane(pk8, 7);
                unsigned u0 = ROWLD(p0 & 0xFFFFFF00);
                unsigned u1 = ROWLD(p1 & 0xFFFFFF00);
                unsigned u2 = ROWLD(p2 & 0xFFFFFF00);
                unsigned u3 = ROWLD(p3 & 0xFFFFFF00);
                unsigned u4 = ROWLD(p4 & 0xFFFFFF00);
                unsigned u5 = ROWLD(p5 & 0xFFFFFF00);
                unsigned u6 = ROWLD(p6 & 0xFFFFFF00);
                unsigned u7 = ROWLD(p7 & 0xFFFFFF00);
                CONSUME(p0, u0);
                CONSUME(p1, u1);
                CONSUME(p2, u2);
                CONSUME(p3, u3);
                CONSUME(p4, u4);
                CONSUME(p5, u5);
                CONSUME(p6, u6);
                CONSUME(p7, u7);
            }
            for (; i + 4 <= end; i += 4) {
                int pk4 = spk[i + (lane & 3)];
                int p0 = __builtin_amdgcn_readlane(pk4, 0);
                int p1 = __builtin_amdgcn_readlane(pk4, 1);
                int p2 = __builtin_amdgcn_readlane(pk4, 2);
                int p3 = __builtin_amdgcn_readlane(pk4, 3);
                unsigned u0 = ROWLD(p0 & 0xFFFFFF00);
                unsigned u1 = ROWLD(p1 & 0xFFFFFF00);
                unsigned u2 = ROWLD(p2 & 0xFFFFFF00);
                unsigned u3 = ROWLD(p3 & 0xFFFFFF00);
                CONSUME(p0, u0);
                CONSUME(p1, u1);
                CONSUME(p2, u2);
                CONSUME(p3, u3);
            }
            for (; i < end; i++) {
                int p = __builtin_amdgcn_readfirstlane(spk[i]);
                unsigned u = ROWLD(p & 0xFFFFFF00);
                CONSUME(p, u);
            }
        }
        #undef CONSUME
        #undef ROWLD

        // scale by precomputed 1/cnt, cvt_pk bf16, swizzled LDS write
        f32x4 iv0 = {0.f, 0.f, 0.f, 0.f}, iv1 = {0.f, 0.f, 0.f, 0.f};
        if (d < N) {
            iv0 = *(const f32x4*)&invc8[(size_t)d * 8];
            iv1 = *(const f32x4*)&invc8[(size_t)d * 8 + 4];
        }
        unsigned swz = (unsigned)(lrow16 & 7) << 4;
        char* rowbase = (char*)lds + (lrow16 << 8);
        unsigned wroff = (((unsigned)lane << 2)) ^ swz;
        #define WR2(R, A, IV)                                               \
        {                                                                   \
            unsigned pk = cvtpk(A.x * (IV), A.y * (IV));                    \
            *(unsigned*)(rowbase + (R << 12) + wroff) = pk;                 \
        }
        WR2(0, a0, iv0[0]) WR2(1, a1, iv0[1]) WR2(2, a2, iv0[2]) WR2(3, a3, iv0[3])
        WR2(4, a4, iv1[0]) WR2(5, a5, iv1[1]) WR2(6, a6, iv1[2]) WR2(7, a7, iv1[3])
        #undef WR2
    }
    __syncthreads();

    // ---------------- phase 2: K-split MFMA, named-batch loads ----------------
    int lrow = lane & 15;
    int kgrp = lane >> 4;
    unsigned swzR = (unsigned)(lrow & 7) << 4;
    const bf16x8* Wf8 = (const bf16x8*)Wf;
    int n0    = wid & 7;                   // n-block (shared by wave pair)
    int upper = wid >> 3;

    f32x4 acc = {0.f, 0.f, 0.f, 0.f};
    const char* abase = (const char*)lds + (lrow << 8);

    int rs0 = upper * 4;
    #pragma unroll 1
    for (int rs = rs0; rs < rs0 + 4; rs++) {
        const bf16x8* Bp = Wf8 + (size_t)rs * 2048 + (size_t)n0 * 64 + lane;
        const char* ab = abase + (rs << 12);
        bf16x8 a0 = *(const bf16x8*)(ab + ((unsigned)(0 * 64 + kgrp * 16) ^ swzR));
        bf16x8 a1 = *(const bf16x8*)(ab + ((unsigned)(1 * 64 + kgrp * 16) ^ swzR));
        bf16x8 a2 = *(const bf16x8*)(ab + ((unsigned)(2 * 64 + kgrp * 16) ^ swzR));
        bf16x8 a3 = *(const bf16x8*)(ab + ((unsigned)(3 * 64 + kgrp * 16) ^ swzR));
        bf16x8 b0 = Bp[0];
        bf16x8 b1 = Bp[512];
        bf16x8 b2 = Bp[1024];
        bf16x8 b3 = Bp[1536];
        acc = __builtin_amdgcn_mfma_f32_16x16x32_bf16(a0, b0, acc, 0, 0, 0);
        acc = __builtin_amdgcn_mfma_f32_16x16x32_bf16(a1, b1, acc, 0, 0, 0);
        acc = __builtin_amdgcn_mfma_f32_16x16x32_bf16(a2, b2, acc, 0, 0, 0);
        acc = __builtin_amdgcn_mfma_f32_16x16x32_bf16(a3, b3, acc, 0, 0, 0);
    }
    {   // root source: upper half does kk 2,3; lower kk 0,1 (from global Xb)
        int arow = blk0 + lrow; if (arow >= N) arow = N - 1;
        const ushort* A = Xb + (size_t)arow * 128;
        const bf16x8* Bp = Wf8 + (size_t)8 * 2048 + (size_t)n0 * 64 + lane;
        int kkb = upper * 2;
        bf16x8 a0 = *(const bf16x8*)(A + (kkb + 0) * 32 + kgrp * 8);
        bf16x8 a1 = *(const bf16x8*)(A + (kkb + 1) * 32 + kgrp * 8);
        bf16x8 b0 = Bp[(kkb + 0) * 512];
        bf16x8 b1 = Bp[(kkb + 1) * 512];
        acc = __builtin_amdgcn_mfma_f32_16x16x32_bf16(a0, b0, acc, 0, 0, 0);
        acc = __builtin_amdgcn_mfma_f32_16x16x32_bf16(a1, b1, acc, 0, 0, 0);
    }

    if (upper) pscr[(size_t)n0 * 64 + lane] = acc;
    __syncthreads();

    if (!upper) {
        f32x4 po = pscr[(size_t)n0 * 64 + lane];
        int row0 = blk0 + kgrp * 4;
        int col  = n0 * 16 + lrow;
        float bv = bias[col];
        #pragma unroll
        for (int r = 0; r < 4; r++) {
            int row = row0 + r;
            float v = acc[r] + po[r] + bv;
            if (relu) v = fmaxf(v, 0.f);
            if (outC) embt[kgrp * 4 + r][col] = v;   // park for classifier
            if (row < N) {
                if (Ofp) Ofp[(size_t)row * 128 + col] = v;
                if (Obf) Obf[(size_t)row * 128 + col] = f2bf(v);
            }
        }
    }

    // ---------------- fused classifier (layer 2 only) ----------------
    if (outC) {
        __syncthreads();
        if (lane < 16) {
            float acc2 = bcs[lane];
            const float* er = embt[wid];
            #pragma unroll 8
            for (int k = 0; k < 128; k++) acc2 += er[k] * wcs[k][lane];
            int row = blk0 + wid;
            if (row < N) outC[(size_t)row * 16 + lane] = acc2;
        }
    }
}

static inline size_t align256(size_t x) { return (x + 255) & ~(size_t)255; }

extern "C" void kernel_launch(void* const* d_in, const int* in_sizes, int n_in,
                              void* d_out, int out_size, void* d_ws, size_t ws_size,
                              hipStream_t stream)
{
    const float* x     = (const float*)d_in[0];
    const int*   ei    = (const int*)d_in[1];
    const int*   et    = (const int*)d_in[2];
    const float* W1    = (const float*)d_in[3];
    const float* root1 = (const float*)d_in[4];
    const float* b1    = (const float*)d_in[5];
    const float* W2    = (const float*)d_in[6];
    const float* root2 = (const float*)d_in[7];
    const float* b2    = (const float*)d_in[8];
    const float* Wc    = (const float*)d_in[9];
    const float* bc    = (const float*)d_in[10];

    const int N = in_sizes[0] / 128;
    const int E = in_sizes[2];
    const int C = in_sizes[10];   // 16

    float* out = (float*)d_out;                 // [N,16]
    float* emb = out + (size_t)N * C;           // [N,128] fp32 (2nd output)

    // ws: cnt | rowptr | cursor | part | bsum | invc8 | spk | xb | hb | Wf1 | Wf2
    size_t cntB  = align256((size_t)NREL * N * sizeof(int));
    size_t rpB   = align256((size_t)(N + 1) * sizeof(int));
    size_t curB  = align256((size_t)N * sizeof(int));
    size_t bsB   = align256((size_t)1024 * sizeof(int));
    size_t invB  = align256((size_t)N * 8 * sizeof(float));
    size_t spkB  = align256((size_t)E * sizeof(int));
    size_t xbB   = align256((size_t)N * 128 * sizeof(ushort));
    size_t wtB   = align256((size_t)128 * 1152 * sizeof(ushort));

    char* p = (char*)d_ws;
    int*    cnt    = (int*)p;      p += cntB;
    int*    rowptr = (int*)p;      p += rpB;
    int*    cursor = (int*)p;      p += curB;
    int*    part   = (int*)p;      p += curB;
    int*    bsum   = (int*)p;      p += bsB;
    float*  invc8  = (float*)p;    p += invB;
    int*    spk    = (int*)p;      p += spkB;
    ushort* xb     = (ushort*)p;   p += xbB;
    ushort* hb     = (ushort*)p;   p += xbB;
    ushort* Wf1    = (ushort*)p;   p += wtB;
    ushort* Wf2    = (ushort*)p;

    dim3 blk(256);
    int gE    = (E + 255) / 256;
    int gN    = (N + 255) / 256;     // <=1024 for scan2
    int gFus  = (N + 15) / 16;       // 3125 blocks of 1024 threads
    int gWt   = (128 * 1152 + 255) / 256;
    long long cnt4 = (long long)NREL * N / 4;
    int gZ = (int)((cnt4 + 255) / 256); if (gZ > 2048) gZ = 2048;
    int nx4 = N * 32;
    int gCx = (nx4 + 255) / 256; if (gCx > 2048) gCx = 2048;

    // ---- CSR build (shared by both layers) ----
    zero16<<<gZ, blk, 0, stream>>>((float4*)cnt, (int)cnt4);
    count_edges<<<gE, blk, 0, stream>>>(ei, et, cnt, E, N);
    scan1f<<<gN, blk, 0, stream>>>(cnt, invc8, part, bsum, N);
    scan2<<<1, 1024, 0, stream>>>(bsum, gN);
    scan3<<<gN, blk, 0, stream>>>(part, bsum, rowptr, cursor, N, E);
    fill_csr<<<gE, blk, 0, stream>>>(ei, et, cursor, spk, E);

    // ---- bf16 conversions ----
    conv_x<<<gCx, blk, 0, stream>>>(x, xb, nx4);
    conv_wfB<<<dim3(gWt, 2), blk, 0, stream>>>(W1, root1, Wf1, W2, root2, Wf2);

    // ---- layer 1: fused gather+GEMM -> hb (bf16, relu) ----
    fused_layer<<<gFus, dim3(1024), 0, stream>>>(
        xb, rowptr, spk, invc8, Wf1, b1, nullptr, hb,
        nullptr, nullptr, nullptr, N, 1);

    // ---- layer 2: fused gather+GEMM+classifier -> emb (fp32) + out ----
    fused_layer<<<gFus, dim3(1024), 0, stream>>>(
        hb, rowptr, spk, invc8, Wf2, b2, emb, nullptr,
        Wc, bc, out, N, 0);
}

// Round 16
// 261.074 us; speedup vs baseline: 1.4682x; 1.0412x over previous
//
#include <hip/hip_runtime.h>

#define NREL 8

typedef __attribute__((ext_vector_type(8))) short bf16x8;
typedef __attribute__((ext_vector_type(4))) float f32x4;

__device__ inline ushort f2bf(float f)
{
    union { float f; unsigned u; } v; v.f = f;
    unsigned r = v.u + 0x7FFF + ((v.u >> 16) & 1);   // RNE
    return (ushort)(r >> 16);
}

// packed RNE f32x2 -> bf16x2 in one instruction (same rounding as f2bf)
__device__ inline unsigned cvtpk(float lo, float hi)
{
    unsigned r;
    asm("v_cvt_pk_bf16_f32 %0, %1, %2" : "=v"(r) : "v"(lo), "v"(hi));
    return r;
}

// ---------------------------------------------------------------------------
// zero16: graph-capturable memset replacement (round-2 lesson).
// ---------------------------------------------------------------------------
__global__ __launch_bounds__(256) void zero16(float4* __restrict__ p, int n4)
{
    int i = blockIdx.x * 256 + threadIdx.x;
    int stride = gridDim.x * 256;
    for (; i < n4; i += stride) p[i] = make_float4(0.f, 0.f, 0.f, 0.f);
}

// ---------------------------------------------------------------------------
// CSR build: count -> fused{totals+inv+scan} -> scan2 -> scan3 -> fill.
// ---------------------------------------------------------------------------
__global__ __launch_bounds__(256) void count_edges(
    const int* __restrict__ ei, const int* __restrict__ et,
    int* __restrict__ cnt, int E, int N)
{
    int e = blockIdx.x * 256 + threadIdx.x;
    if (e < E) {
        int d = ei[E + e];
        int r = et[e];
        atomicAdd(&cnt[r * N + d], 1);
    }
}

__global__ __launch_bounds__(256) void scan1f(
    const int* __restrict__ cnt, float* __restrict__ invc8,
    int* __restrict__ part, int* __restrict__ bsum, int N)
{
    __shared__ int tmp[256];
    int d = blockIdx.x * 256 + threadIdx.x;
    int s = 0;
    if (d < N) {
        #pragma unroll
        for (int r = 0; r < NREL; r++) {
            int c = cnt[r * N + d];
            s += c;
            invc8[(size_t)d * 8 + r] = (c > 0) ? 1.f / (float)c : 0.f;
        }
    }
    int v = s;
    tmp[threadIdx.x] = v;
    __syncthreads();
    for (int off = 1; off < 256; off <<= 1) {
        int t = (threadIdx.x >= off) ? tmp[threadIdx.x - off] : 0;
        __syncthreads();
        tmp[threadIdx.x] += t;
        __syncthreads();
    }
    if (d < N) part[d] = tmp[threadIdx.x] - v;
    if (threadIdx.x == 255) bsum[blockIdx.x] = tmp[255];
}

__global__ __launch_bounds__(1024) void scan2(int* __restrict__ bsum, int nb)
{
    __shared__ int tmp[1024];
    int tid = threadIdx.x;
    int v = (tid < nb) ? bsum[tid] : 0;
    tmp[tid] = v;
    __syncthreads();
    for (int off = 1; off < 1024; off <<= 1) {
        int t = (tid >= off) ? tmp[tid - off] : 0;
        __syncthreads();
        tmp[tid] += t;
        __syncthreads();
    }
    if (tid < nb) bsum[tid] = tmp[tid] - v;
}

__global__ __launch_bounds__(256) void scan3(
    const int* __restrict__ part, const int* __restrict__ bsum,
    int* __restrict__ rowptr, int* __restrict__ cursor, int n, int E)
{
    int i = blockIdx.x * 256 + threadIdx.x;
    if (i < n) {
        int v = part[i] + bsum[blockIdx.x];
        rowptr[i] = v;
        cursor[i] = v;
    }
    if (i == 0) rowptr[n] = E;
}

// spk packs (src << 8) | rel  ->  row byte-offset = pk & 0xFFFFFF00
__global__ __launch_bounds__(256) void fill_csr(
    const int* __restrict__ ei, const int* __restrict__ et,
    int* __restrict__ cursor, int* __restrict__ spk, int E)
{
    int e = blockIdx.x * 256 + threadIdx.x;
    if (e < E) {
        int d = ei[E + e];
        int pos = atomicAdd(&cursor[d], 1);
        spk[pos] = (ei[e] << 8) | et[e];
    }
}

// ---------------------------------------------------------------------------
// conv_x: fp32 activations -> bf16, contiguous.
// ---------------------------------------------------------------------------
__global__ __launch_bounds__(256) void conv_x(
    const float* __restrict__ x, ushort* __restrict__ xb, int n4)
{
    int i = blockIdx.x * 256 + threadIdx.x;
    int stride = gridDim.x * 256;
    for (; i < n4; i += stride) {
        float4 v = ((const float4*)x)[i];
        ushort4 o;
        o.x = f2bf(v.x); o.y = f2bf(v.y); o.z = f2bf(v.z); o.w = f2bf(v.w);
        ((ushort4*)xb)[i] = o;
    }
}

// ---------------------------------------------------------------------------
// conv_wfB: both layers' weights -> bf16 MFMA-fragment order; y picks layer.
// ---------------------------------------------------------------------------
__global__ __launch_bounds__(256) void conv_wfB(
    const float* __restrict__ W1, const float* __restrict__ root1,
    ushort* __restrict__ Wf1,
    const float* __restrict__ W2, const float* __restrict__ root2,
    ushort* __restrict__ Wf2)
{
    const float* W    = blockIdx.y ? W2 : W1;
    const float* root = blockIdx.y ? root2 : root1;
    ushort* Wf        = blockIdx.y ? Wf2 : Wf1;
    int i = blockIdx.x * 256 + threadIdx.x;
    if (i >= 128 * 1152) return;
    int f = i >> 9;
    int within = i & 511;
    int l = within >> 3;
    int j = within & 7;
    int rs = f >> 5;
    int kk = (f >> 3) & 3;
    int n  = f & 7;
    int col = (n << 4) | (l & 15);
    int kl  = kk * 32 + (l >> 4) * 8 + j;
    float v = (rs < 8) ? W[rs * 16384 + kl * 128 + col] : root[kl * 128 + col];
    Wf[i] = f2bf(v);
}

// ---------------------------------------------------------------------------
// FUSED gather + MFMA, v5 (round-16): M=32 rows/block to HALVE per-row
// B-fragment L2 traffic (round-15 post-mortem: 113us pinned across 3 rounds
// while VALUBusy fell 47->41% -> VALU not the bound; candidate (a) = Wf
// re-reads from L2, 18KB/wave at M=16 = 0.9GB/layer ~ 26us).
// Phase 1: 16 waves x 2 rows each (serial walk, diet'd).
// Phase 2: K-split as before, but each B-fragment feeds TWO row-groups
// (acc0 rows 0-15, acc1 rows 16-31) -> 9KB B-bytes per row.
// LDS: 64KB A-tile [8rs][32][128] + 16KB pscr = 80KB -> 2 blocks/CU (32 wv).
// launch_bounds(1024,8) pins VGPR<=64 so 2 blocks actually fit.
// If this lands ~113 unchanged -> gather straggler owns the time (pivot).
// ---------------------------------------------------------------------------
__global__ __launch_bounds__(1024, 8) void fused_layer(
    const ushort* __restrict__ Xb, const int* __restrict__ rowptr,
    const int* __restrict__ spk, const float* __restrict__ invc8,
    const ushort* __restrict__ Wf, const float* __restrict__ bias,
    float* __restrict__ Ofp, ushort* __restrict__ Obf, int N, int relu)
{
    __shared__ ushort lds[8 * 32 * 128];   // 64 KB aggregated-A tile
    __shared__ f32x4 pscr[2][512];         // 16 KB partial accumulators

    int wid  = threadIdx.x >> 6;           // 0..15
    int lane = threadIdx.x & 63;
    int blk0 = blockIdx.x * 32;
    int lane4 = lane << 2;

    // ---------------- phase 1: gather TWO rows per wave ----------------
    #pragma unroll 1
    for (int rr = 0; rr < 2; rr++) {
        int lrow32 = wid * 2 + rr;
        int d = blk0 + lrow32;

        float2 a0 = {0.f, 0.f}, a1 = {0.f, 0.f}, a2 = {0.f, 0.f}, a3 = {0.f, 0.f};
        float2 a4 = {0.f, 0.f}, a5 = {0.f, 0.f}, a6 = {0.f, 0.f}, a7 = {0.f, 0.f};

        #define ROWLD(SP) \
            (*(const unsigned*)((const char*)Xb + (unsigned)((SP) | lane4)))
        #define CONSUME(P, U)                                               \
        {                                                                   \
            union { unsigned u; float f; } lo, hi;                          \
            lo.u = (U) << 16; hi.u = (U) & 0xFFFF0000u;                     \
            switch ((P) & 0xFF) {                                           \
                case 0: a0.x += lo.f; a0.y += hi.f; break;                  \
                case 1: a1.x += lo.f; a1.y += hi.f; break;                  \
                case 2: a2.x += lo.f; a2.y += hi.f; break;                  \
                case 3: a3.x += lo.f; a3.y += hi.f; break;                  \
                case 4: a4.x += lo.f; a4.y += hi.f; break;                  \
                case 5: a5.x += lo.f; a5.y += hi.f; break;                  \
                case 6: a6.x += lo.f; a6.y += hi.f; break;                  \
                default: a7.x += lo.f; a7.y += hi.f; break;                 \
            }                                                               \
        }

        if (d < N) {
            int beg = rowptr[d], end = rowptr[d + 1];
            int i = beg;
            for (; i + 8 <= end; i += 8) {
                int pk8 = spk[i + (lane & 7)];
                int p0 = __builtin_amdgcn_readlane(pk8, 0);
                int p1 = __builtin_amdgcn_readlane(pk8, 1);
                int p2 = __builtin_amdgcn_readlane(pk8, 2);
                int p3 = __builtin_amdgcn_readlane(pk8, 3);
                int p4 = __builtin_amdgcn_readlane(pk8, 4);
                int p5 = __builtin_amdgcn_readlane(pk8, 5);
                int p6 = __builtin_amdgcn_readlane(pk8, 6);
                int p7 = __builtin_amdgcn_readlane(pk8, 7);
                unsigned u0 = ROWLD(p0 & 0xFFFFFF00);
                unsigned u1 = ROWLD(p1 & 0xFFFFFF00);
                unsigned u2 = ROWLD(p2 & 0xFFFFFF00);
                unsigned u3 = ROWLD(p3 & 0xFFFFFF00);
                unsigned u4 = ROWLD(p4 & 0xFFFFFF00);
                unsigned u5 = ROWLD(p5 & 0xFFFFFF00);
                unsigned u6 = ROWLD(p6 & 0xFFFFFF00);
                unsigned u7 = ROWLD(p7 & 0xFFFFFF00);
                CONSUME(p0, u0);
                CONSUME(p1, u1);
                CONSUME(p2, u2);
                CONSUME(p3, u3);
                CONSUME(p4, u4);
                CONSUME(p5, u5);
                CONSUME(p6, u6);
                CONSUME(p7, u7);
            }
            for (; i + 4 <= end; i += 4) {
                int pk4 = spk[i + (lane & 3)];
                int p0 = __builtin_amdgcn_readlane(pk4, 0);
                int p1 = __builtin_amdgcn_readlane(pk4, 1);
                int p2 = __builtin_amdgcn_readlane(pk4, 2);
                int p3 = __builtin_amdgcn_readlane(pk4, 3);
                unsigned u0 = ROWLD(p0 & 0xFFFFFF00);
                unsigned u1 = ROWLD(p1 & 0xFFFFFF00);
                unsigned u2 = ROWLD(p2 & 0xFFFFFF00);
                unsigned u3 = ROWLD(p3 & 0xFFFFFF00);
                CONSUME(p0, u0);
                CONSUME(p1, u1);
                CONSUME(p2, u2);
                CONSUME(p3, u3);
            }
            for (; i < end; i++) {
                int p = __builtin_amdgcn_readfirstlane(spk[i]);
                unsigned u = ROWLD(p & 0xFFFFFF00);
                CONSUME(p, u);
            }
        }
        #undef CONSUME
        #undef ROWLD

        f32x4 iv0 = {0.f, 0.f, 0.f, 0.f}, iv1 = {0.f, 0.f, 0.f, 0.f};
        if (d < N) {
            iv0 = *(const f32x4*)&invc8[(size_t)d * 8];
            iv1 = *(const f32x4*)&invc8[(size_t)d * 8 + 4];
        }
        unsigned swz = (unsigned)(lrow32 & 7) << 4;
        char* rowbase = (char*)lds + (lrow32 << 8);
        unsigned wroff = (((unsigned)lane << 2)) ^ swz;
        #define WR2(R, A, IV)                                               \
        {                                                                   \
            unsigned pk = cvtpk(A.x * (IV), A.y * (IV));                    \
            *(unsigned*)(rowbase + (R << 13) + wroff) = pk;                 \
        }
        WR2(0, a0, iv0[0]) WR2(1, a1, iv0[1]) WR2(2, a2, iv0[2]) WR2(3, a3, iv0[3])
        WR2(4, a4, iv1[0]) WR2(5, a5, iv1[1]) WR2(6, a6, iv1[2]) WR2(7, a7, iv1[3])
        #undef WR2
    }
    __syncthreads();

    // ---------------- phase 2: K-split MFMA, 2 row-groups per B ----------------
    int lrow = lane & 15;
    int kgrp = lane >> 4;
    unsigned swzR = (unsigned)(lrow & 7) << 4;
    const bf16x8* Wf8 = (const bf16x8*)Wf;
    int n0    = wid & 7;
    int upper = wid >> 3;

    f32x4 acc0 = {0.f, 0.f, 0.f, 0.f};
    f32x4 acc1 = {0.f, 0.f, 0.f, 0.f};
    const char* ldsb = (const char*)lds;

    int rs0 = upper * 4;
    #pragma unroll 1
    for (int rs = rs0; rs < rs0 + 4; rs++) {
        const bf16x8* Bp = Wf8 + (size_t)rs * 2048 + (size_t)n0 * 64 + lane;
        bf16x8 b0 = Bp[0];
        bf16x8 b1 = Bp[512];
        bf16x8 b2 = Bp[1024];
        bf16x8 b3 = Bp[1536];
        const char* ab0 = ldsb + (rs << 13) + ((0 + lrow) << 8);
        const char* ab1 = ldsb + (rs << 13) + ((16 + lrow) << 8);
        // row-group 0
        {
            bf16x8 a0 = *(const bf16x8*)(ab0 + ((unsigned)(0 * 64 + kgrp * 16) ^ swzR));
            bf16x8 a1 = *(const bf16x8*)(ab0 + ((unsigned)(1 * 64 + kgrp * 16) ^ swzR));
            bf16x8 a2 = *(const bf16x8*)(ab0 + ((unsigned)(2 * 64 + kgrp * 16) ^ swzR));
            bf16x8 a3 = *(const bf16x8*)(ab0 + ((unsigned)(3 * 64 + kgrp * 16) ^ swzR));
            acc0 = __builtin_amdgcn_mfma_f32_16x16x32_bf16(a0, b0, acc0, 0, 0, 0);
            acc0 = __builtin_amdgcn_mfma_f32_16x16x32_bf16(a1, b1, acc0, 0, 0, 0);
            acc0 = __builtin_amdgcn_mfma_f32_16x16x32_bf16(a2, b2, acc0, 0, 0, 0);
            acc0 = __builtin_amdgcn_mfma_f32_16x16x32_bf16(a3, b3, acc0, 0, 0, 0);
        }
        // row-group 1 (same B fragments — the M32 reuse)
        {
            bf16x8 a0 = *(const bf16x8*)(ab1 + ((unsigned)(0 * 64 + kgrp * 16) ^ swzR));
            bf16x8 a1 = *(const bf16x8*)(ab1 + ((unsigned)(1 * 64 + kgrp * 16) ^ swzR));
            bf16x8 a2 = *(const bf16x8*)(ab1 + ((unsigned)(2 * 64 + kgrp * 16) ^ swzR));
            bf16x8 a3 = *(const bf16x8*)(ab1 + ((unsigned)(3 * 64 + kgrp * 16) ^ swzR));
            acc1 = __builtin_amdgcn_mfma_f32_16x16x32_bf16(a0, b0, acc1, 0, 0, 0);
            acc1 = __builtin_amdgcn_mfma_f32_16x16x32_bf16(a1, b1, acc1, 0, 0, 0);
            acc1 = __builtin_amdgcn_mfma_f32_16x16x32_bf16(a2, b2, acc1, 0, 0, 0);
            acc1 = __builtin_amdgcn_mfma_f32_16x16x32_bf16(a3, b3, acc1, 0, 0, 0);
        }
    }
    {   // root source from global Xb: upper half kk 2,3; lower kk 0,1
        int arow0 = blk0 + lrow;      if (arow0 >= N) arow0 = N - 1;
        int arow1 = blk0 + 16 + lrow; if (arow1 >= N) arow1 = N - 1;
        const ushort* A0 = Xb + (size_t)arow0 * 128;
        const ushort* A1 = Xb + (size_t)arow1 * 128;
        const bf16x8* Bp = Wf8 + (size_t)8 * 2048 + (size_t)n0 * 64 + lane;
        int kkb = upper * 2;
        bf16x8 b0 = Bp[(kkb + 0) * 512];
        bf16x8 b1 = Bp[(kkb + 1) * 512];
        bf16x8 a00 = *(const bf16x8*)(A0 + (kkb + 0) * 32 + kgrp * 8);
        bf16x8 a01 = *(const bf16x8*)(A0 + (kkb + 1) * 32 + kgrp * 8);
        bf16x8 a10 = *(const bf16x8*)(A1 + (kkb + 0) * 32 + kgrp * 8);
        bf16x8 a11 = *(const bf16x8*)(A1 + (kkb + 1) * 32 + kgrp * 8);
        acc0 = __builtin_amdgcn_mfma_f32_16x16x32_bf16(a00, b0, acc0, 0, 0, 0);
        acc0 = __builtin_amdgcn_mfma_f32_16x16x32_bf16(a01, b1, acc0, 0, 0, 0);
        acc1 = __builtin_amdgcn_mfma_f32_16x16x32_bf16(a10, b0, acc1, 0, 0, 0);
        acc1 = __builtin_amdgcn_mfma_f32_16x16x32_bf16(a11, b1, acc1, 0, 0, 0);
    }

    if (upper) {
        pscr[0][n0 * 64 + lane] = acc0;
        pscr[1][n0 * 64 + lane] = acc1;
    }
    __syncthreads();

    if (!upper) {
        f32x4 p0 = pscr[0][n0 * 64 + lane];
        f32x4 p1 = pscr[1][n0 * 64 + lane];
        int col = n0 * 16 + lrow;
        float bv = bias[col];
        #pragma unroll
        for (int rg = 0; rg < 2; rg++) {
            int row0 = blk0 + rg * 16 + kgrp * 4;
            f32x4 a = rg ? acc1 : acc0;
            f32x4 pp = rg ? p1 : p0;
            #pragma unroll
            for (int r = 0; r < 4; r++) {
                int row = row0 + r;
                if (row < N) {
                    float v = a[r] + pp[r] + bv;
                    if (relu) v = fmaxf(v, 0.f);
                    if (Ofp) Ofp[(size_t)row * 128 + col] = v;
                    if (Obf) Obf[(size_t)row * 128 + col] = f2bf(v);
                }
            }
        }
    }
}

// ---------------------------------------------------------------------------
// out[n][c] = sum_k emb[n][k] * Wc[k*16+c] + bc[c];   16 nodes / block
// (separate again: M32 LDS budget evicted the fused classifier; emb is
// L2/L3-hot right after layer 2, so this is ~8us)
// ---------------------------------------------------------------------------
__global__ __launch_bounds__(256) void classifier(
    const float* __restrict__ emb, const float* __restrict__ Wc,
    const float* __restrict__ bc, float* __restrict__ out, int N)
{
    int t = threadIdx.x;
    int c = t & 15;
    int n = blockIdx.x * 16 + (t >> 4);
    if (n >= N) return;
    const float* e = emb + (size_t)n * 128;
    float acc = bc[c];
    #pragma unroll 8
    for (int k = 0; k < 128; k++) acc += e[k] * Wc[k * 16 + c];
    out[(size_t)n * 16 + c] = acc;
}

static inline size_t align256(size_t x) { return (x + 255) & ~(size_t)255; }

extern "C" void kernel_launch(void* const* d_in, const int* in_sizes, int n_in,
                              void* d_out, int out_size, void* d_ws, size_t ws_size,
                              hipStream_t stream)
{
    const float* x     = (const float*)d_in[0];
    const int*   ei    = (const int*)d_in[1];
    const int*   et    = (const int*)d_in[2];
    const float* W1    = (const float*)d_in[3];
    const float* root1 = (const float*)d_in[4];
    const float* b1    = (const float*)d_in[5];
    const float* W2    = (const float*)d_in[6];
    const float* root2 = (const float*)d_in[7];
    const float* b2    = (const float*)d_in[8];
    const float* Wc    = (const float*)d_in[9];
    const float* bc    = (const float*)d_in[10];

    const int N = in_sizes[0] / 128;
    const int E = in_sizes[2];
    const int C = in_sizes[10];   // 16

    float* out = (float*)d_out;                 // [N,16]
    float* emb = out + (size_t)N * C;           // [N,128] fp32 (2nd output)

    // ws: cnt | rowptr | cursor | part | bsum | invc8 | spk | xb | hb | Wf1 | Wf2
    size_t cntB  = align256((size_t)NREL * N * sizeof(int));
    size_t rpB   = align256((size_t)(N + 1) * sizeof(int));
    size_t curB  = align256((size_t)N * sizeof(int));
    size_t bsB   = align256((size_t)1024 * sizeof(int));
    size_t invB  = align256((size_t)N * 8 * sizeof(float));
    size_t spkB  = align256((size_t)E * sizeof(int));
    size_t xbB   = align256((size_t)N * 128 * sizeof(ushort));
    size_t wtB   = align256((size_t)128 * 1152 * sizeof(ushort));

    char* p = (char*)d_ws;
    int*    cnt    = (int*)p;      p += cntB;
    int*    rowptr = (int*)p;      p += rpB;
    int*    cursor = (int*)p;      p += curB;
    int*    part   = (int*)p;      p += curB;
    int*    bsum   = (int*)p;      p += bsB;
    float*  invc8  = (float*)p;    p += invB;
    int*    spk    = (int*)p;      p += spkB;
    ushort* xb     = (ushort*)p;   p += xbB;
    ushort* hb     = (ushort*)p;   p += xbB;
    ushort* Wf1    = (ushort*)p;   p += wtB;
    ushort* Wf2    = (ushort*)p;

    dim3 blk(256);
    int gE    = (E + 255) / 256;
    int gN    = (N + 255) / 256;     // <=1024 for scan2
    int gFus  = (N + 31) / 32;       // 1563 blocks of 1024 threads
    int gCls  = (N + 15) / 16;
    int gWt   = (128 * 1152 + 255) / 256;
    long long cnt4 = (long long)NREL * N / 4;
    int gZ = (int)((cnt4 + 255) / 256); if (gZ > 2048) gZ = 2048;
    int nx4 = N * 32;
    int gCx = (nx4 + 255) / 256; if (gCx > 2048) gCx = 2048;

    // ---- CSR build (shared by both layers) ----
    zero16<<<gZ, blk, 0, stream>>>((float4*)cnt, (int)cnt4);
    count_edges<<<gE, blk, 0, stream>>>(ei, et, cnt, E, N);
    scan1f<<<gN, blk, 0, stream>>>(cnt, invc8, part, bsum, N);
    scan2<<<1, 1024, 0, stream>>>(bsum, gN);
    scan3<<<gN, blk, 0, stream>>>(part, bsum, rowptr, cursor, N, E);
    fill_csr<<<gE, blk, 0, stream>>>(ei, et, cursor, spk, E);

    // ---- bf16 conversions ----
    conv_x<<<gCx, blk, 0, stream>>>(x, xb, nx4);
    conv_wfB<<<dim3(gWt, 2), blk, 0, stream>>>(W1, root1, Wf1, W2, root2, Wf2);

    // ---- layer 1: fused gather+GEMM -> hb (bf16, relu) ----
    fused_layer<<<gFus, dim3(1024), 0, stream>>>(
        xb, rowptr, spk, invc8, Wf1, b1, nullptr, hb, N, 1);

    // ---- layer 2: fused gather+GEMM -> emb (fp32) ----
    fused_layer<<<gFus, dim3(1024), 0, stream>>>(
        hb, rowptr, spk, invc8, Wf2, b2, emb, nullptr, N, 0);

    // ---- classifier ----
    classifier<<<gCls, blk, 0, stream>>>(emb, Wc, bc, out, N);
}

// Round 17
// 236.441 us; speedup vs baseline: 1.6211x; 1.1042x over previous
//
#include <hip/hip_runtime.h>

#define NREL 8

typedef __attribute__((ext_vector_type(8))) short bf16x8;
typedef __attribute__((ext_vector_type(4))) float f32x4;

__device__ inline ushort f2bf(float f)
{
    union { float f; unsigned u; } v; v.f = f;
    unsigned r = v.u + 0x7FFF + ((v.u >> 16) & 1);   // RNE
    return (ushort)(r >> 16);
}

// packed RNE f32x2 -> bf16x2 in one instruction (same rounding as f2bf)
__device__ inline unsigned cvtpk(float lo, float hi)
{
    unsigned r;
    asm("v_cvt_pk_bf16_f32 %0, %1, %2" : "=v"(r) : "v"(lo), "v"(hi));
    return r;
}

// ---------------------------------------------------------------------------
// prep1 (round-17): zero cnt + conv_x + conv_wf(both layers) in ONE kernel
// (all three independent; 3 grid-stride sections). Replaces 3 launches.
// ---------------------------------------------------------------------------
__global__ __launch_bounds__(256) void prep1(
    float4* __restrict__ cntz, int cnt4,
    const float* __restrict__ x, ushort* __restrict__ xb, int nx4,
    const float* __restrict__ W1, const float* __restrict__ root1,
    ushort* __restrict__ Wf1,
    const float* __restrict__ W2, const float* __restrict__ root2,
    ushort* __restrict__ Wf2)
{
    int tid = blockIdx.x * 256 + threadIdx.x;
    int stride = gridDim.x * 256;

    for (int i = tid; i < cnt4; i += stride)
        cntz[i] = make_float4(0.f, 0.f, 0.f, 0.f);

    for (int i = tid; i < nx4; i += stride) {
        float4 v = ((const float4*)x)[i];
        ushort4 o;
        o.x = f2bf(v.x); o.y = f2bf(v.y); o.z = f2bf(v.z); o.w = f2bf(v.w);
        ((ushort4*)xb)[i] = o;
    }

    const int WFN = 128 * 1152;
    for (int i = tid; i < 2 * WFN; i += stride) {
        int half = (i >= WFN);
        int j = half ? i - WFN : i;
        const float* W    = half ? W2 : W1;
        const float* root = half ? root2 : root1;
        ushort* Wf        = half ? Wf2 : Wf1;
        int f = j >> 9;
        int within = j & 511;
        int l = within >> 3;
        int jj = within & 7;
        int rs = f >> 5;
        int kk = (f >> 3) & 3;
        int n  = f & 7;
        int col = (n << 4) | (l & 15);
        int kl  = kk * 32 + (l >> 4) * 8 + jj;
        float v = (rs < 8) ? W[rs * 16384 + kl * 128 + col]
                           : root[kl * 128 + col];
        Wf[j] = f2bf(v);
    }
}

// ---------------------------------------------------------------------------
// CSR build: count -> fused{totals+inv+scan} -> scan2 -> scan3 -> fill.
// ---------------------------------------------------------------------------
__global__ __launch_bounds__(256) void count_edges(
    const int* __restrict__ ei, const int* __restrict__ et,
    int* __restrict__ cnt, int E, int N)
{
    int e = blockIdx.x * 256 + threadIdx.x;
    if (e < E) {
        int d = ei[E + e];
        int r = et[e];
        atomicAdd(&cnt[r * N + d], 1);
    }
}

__global__ __launch_bounds__(256) void scan1f(
    const int* __restrict__ cnt, float* __restrict__ invc8,
    int* __restrict__ part, int* __restrict__ bsum, int N)
{
    __shared__ int tmp[256];
    int d = blockIdx.x * 256 + threadIdx.x;
    int s = 0;
    if (d < N) {
        #pragma unroll
        for (int r = 0; r < NREL; r++) {
            int c = cnt[r * N + d];
            s += c;
            invc8[(size_t)d * 8 + r] = (c > 0) ? 1.f / (float)c : 0.f;
        }
    }
    int v = s;
    tmp[threadIdx.x] = v;
    __syncthreads();
    for (int off = 1; off < 256; off <<= 1) {
        int t = (threadIdx.x >= off) ? tmp[threadIdx.x - off] : 0;
        __syncthreads();
        tmp[threadIdx.x] += t;
        __syncthreads();
    }
    if (d < N) part[d] = tmp[threadIdx.x] - v;
    if (threadIdx.x == 255) bsum[blockIdx.x] = tmp[255];
}

__global__ __launch_bounds__(1024) void scan2(int* __restrict__ bsum, int nb)
{
    __shared__ int tmp[1024];
    int tid = threadIdx.x;
    int v = (tid < nb) ? bsum[tid] : 0;
    tmp[tid] = v;
    __syncthreads();
    for (int off = 1; off < 1024; off <<= 1) {
        int t = (tid >= off) ? tmp[tid - off] : 0;
        __syncthreads();
        tmp[tid] += t;
        __syncthreads();
    }
    if (tid < nb) bsum[tid] = tmp[tid] - v;
}

__global__ __launch_bounds__(256) void scan3(
    const int* __restrict__ part, const int* __restrict__ bsum,
    int* __restrict__ rowptr, int* __restrict__ cursor, int n, int E)
{
    int i = blockIdx.x * 256 + threadIdx.x;
    if (i < n) {
        int v = part[i] + bsum[blockIdx.x];
        rowptr[i] = v;
        cursor[i] = v;
    }
    if (i == 0) rowptr[n] = E;
}

// spk packs (src << 8) | rel  ->  row byte-offset = pk & 0xFFFFFF00
__global__ __launch_bounds__(256) void fill_csr(
    const int* __restrict__ ei, const int* __restrict__ et,
    int* __restrict__ cursor, int* __restrict__ spk, int E)
{
    int e = blockIdx.x * 256 + threadIdx.x;
    if (e < E) {
        int d = ei[E + e];
        int pos = atomicAdd(&cursor[d], 1);
        spk[pos] = (ei[e] << 8) | et[e];
    }
}

// ---------------------------------------------------------------------------
// FUSED gather + MFMA (+ layer-2 classifier), v6 (round-17).
// vs round-16: (a) spk-load software pipeline (prefetch next group's spk
// while row loads are in flight); (b) classifier fused into layer-2 with
// ZERO LDS growth — after the pscr barrier all A-tile reads are done, so
// the first 16KB of the A-tile LDS is reused as the emb tile.
// ---------------------------------------------------------------------------
__global__ __launch_bounds__(1024, 8) void fused_layer(
    const ushort* __restrict__ Xb, const int* __restrict__ rowptr,
    const int* __restrict__ spk, const float* __restrict__ invc8,
    const ushort* __restrict__ Wf, const float* __restrict__ bias,
    float* __restrict__ Ofp, ushort* __restrict__ Obf,
    const float* __restrict__ Wc, const float* __restrict__ bc,
    float* __restrict__ outC, int N, int relu)
{
    __shared__ ushort lds[8 * 32 * 128];   // 64 KB A-tile; tail-reused as embt
    __shared__ f32x4 pscr[2][512];         // 16 KB partial accumulators

    int wid  = threadIdx.x >> 6;           // 0..15
    int lane = threadIdx.x & 63;
    int blk0 = blockIdx.x * 32;
    int lane4 = lane << 2;

    // ---------------- phase 1: gather TWO rows per wave ----------------
    #pragma unroll 1
    for (int rr = 0; rr < 2; rr++) {
        int lrow32 = wid * 2 + rr;
        int d = blk0 + lrow32;

        float2 a0 = {0.f, 0.f}, a1 = {0.f, 0.f}, a2 = {0.f, 0.f}, a3 = {0.f, 0.f};
        float2 a4 = {0.f, 0.f}, a5 = {0.f, 0.f}, a6 = {0.f, 0.f}, a7 = {0.f, 0.f};

        #define ROWLD(SP) \
            (*(const unsigned*)((const char*)Xb + (unsigned)((SP) | lane4)))
        #define CONSUME(P, U)                                               \
        {                                                                   \
            union { unsigned u; float f; } lo, hi;                          \
            lo.u = (U) << 16; hi.u = (U) & 0xFFFF0000u;                     \
            switch ((P) & 0xFF) {                                           \
                case 0: a0.x += lo.f; a0.y += hi.f; break;                  \
                case 1: a1.x += lo.f; a1.y += hi.f; break;                  \
                case 2: a2.x += lo.f; a2.y += hi.f; break;                  \
                case 3: a3.x += lo.f; a3.y += hi.f; break;                  \
                case 4: a4.x += lo.f; a4.y += hi.f; break;                  \
                case 5: a5.x += lo.f; a5.y += hi.f; break;                  \
                case 6: a6.x += lo.f; a6.y += hi.f; break;                  \
                default: a7.x += lo.f; a7.y += hi.f; break;                 \
            }                                                               \
        }

        if (d < N) {
            int beg = rowptr[d], end = rowptr[d + 1];
            int i = beg;
            // software-pipelined 8-deep groups: next spk prefetched while
            // current group's row loads are in flight
            int pk8 = (i + 8 <= end) ? spk[i + (lane & 7)] : 0;
            for (; i + 8 <= end; ) {
                int cur = pk8;
                i += 8;
                if (i + 8 <= end) pk8 = spk[i + (lane & 7)];
                int p0 = __builtin_amdgcn_readlane(cur, 0);
                int p1 = __builtin_amdgcn_readlane(cur, 1);
                int p2 = __builtin_amdgcn_readlane(cur, 2);
                int p3 = __builtin_amdgcn_readlane(cur, 3);
                int p4 = __builtin_amdgcn_readlane(cur, 4);
                int p5 = __builtin_amdgcn_readlane(cur, 5);
                int p6 = __builtin_amdgcn_readlane(cur, 6);
                int p7 = __builtin_amdgcn_readlane(cur, 7);
                unsigned u0 = ROWLD(p0 & 0xFFFFFF00);
                unsigned u1 = ROWLD(p1 & 0xFFFFFF00);
                unsigned u2 = ROWLD(p2 & 0xFFFFFF00);
                unsigned u3 = ROWLD(p3 & 0xFFFFFF00);
                unsigned u4 = ROWLD(p4 & 0xFFFFFF00);
                unsigned u5 = ROWLD(p5 & 0xFFFFFF00);
                unsigned u6 = ROWLD(p6 & 0xFFFFFF00);
                unsigned u7 = ROWLD(p7 & 0xFFFFFF00);
                CONSUME(p0, u0);
                CONSUME(p1, u1);
                CONSUME(p2, u2);
                CONSUME(p3, u3);
                CONSUME(p4, u4);
                CONSUME(p5, u5);
                CONSUME(p6, u6);
                CONSUME(p7, u7);
            }
            for (; i + 4 <= end; i += 4) {
                int pk4 = spk[i + (lane & 3)];
                int p0 = __builtin_amdgcn_readlane(pk4, 0);
                int p1 = __builtin_amdgcn_readlane(pk4, 1);
                int p2 = __builtin_amdgcn_readlane(pk4, 2);
                int p3 = __builtin_amdgcn_readlane(pk4, 3);
                unsigned u0 = ROWLD(p0 & 0xFFFFFF00);
                unsigned u1 = ROWLD(p1 & 0xFFFFFF00);
                unsigned u2 = ROWLD(p2 & 0xFFFFFF00);
                unsigned u3 = ROWLD(p3 & 0xFFFFFF00);
                CONSUME(p0, u0);
                CONSUME(p1, u1);
                CONSUME(p2, u2);
                CONSUME(p3, u3);
            }
            for (; i < end; i++) {
                int p = __builtin_amdgcn_readfirstlane(spk[i]);
                unsigned u = ROWLD(p & 0xFFFFFF00);
                CONSUME(p, u);
            }
        }
        #undef CONSUME
        #undef ROWLD

        f32x4 iv0 = {0.f, 0.f, 0.f, 0.f}, iv1 = {0.f, 0.f, 0.f, 0.f};
        if (d < N) {
            iv0 = *(const f32x4*)&invc8[(size_t)d * 8];
            iv1 = *(const f32x4*)&invc8[(size_t)d * 8 + 4];
        }
        unsigned swz = (unsigned)(lrow32 & 7) << 4;
        char* rowbase = (char*)lds + (lrow32 << 8);
        unsigned wroff = (((unsigned)lane << 2)) ^ swz;
        #define WR2(R, A, IV)                                               \
        {                                                                   \
            unsigned pk = cvtpk(A.x * (IV), A.y * (IV));                    \
            *(unsigned*)(rowbase + (R << 13) + wroff) = pk;                 \
        }
        WR2(0, a0, iv0[0]) WR2(1, a1, iv0[1]) WR2(2, a2, iv0[2]) WR2(3, a3, iv0[3])
        WR2(4, a4, iv1[0]) WR2(5, a5, iv1[1]) WR2(6, a6, iv1[2]) WR2(7, a7, iv1[3])
        #undef WR2
    }
    __syncthreads();

    // ---------------- phase 2: K-split MFMA, 2 row-groups per B ----------------
    int lrow = lane & 15;
    int kgrp = lane >> 4;
    unsigned swzR = (unsigned)(lrow & 7) << 4;
    const bf16x8* Wf8 = (const bf16x8*)Wf;
    int n0    = wid & 7;
    int upper = wid >> 3;

    f32x4 acc0 = {0.f, 0.f, 0.f, 0.f};
    f32x4 acc1 = {0.f, 0.f, 0.f, 0.f};
    const char* ldsb = (const char*)lds;

    int rs0 = upper * 4;
    #pragma unroll 1
    for (int rs = rs0; rs < rs0 + 4; rs++) {
        const bf16x8* Bp = Wf8 + (size_t)rs * 2048 + (size_t)n0 * 64 + lane;
        bf16x8 b0 = Bp[0];
        bf16x8 b1 = Bp[512];
        bf16x8 b2 = Bp[1024];
        bf16x8 b3 = Bp[1536];
        const char* ab0 = ldsb + (rs << 13) + ((0 + lrow) << 8);
        const char* ab1 = ldsb + (rs << 13) + ((16 + lrow) << 8);
        {
            bf16x8 a0 = *(const bf16x8*)(ab0 + ((unsigned)(0 * 64 + kgrp * 16) ^ swzR));
            bf16x8 a1 = *(const bf16x8*)(ab0 + ((unsigned)(1 * 64 + kgrp * 16) ^ swzR));
            bf16x8 a2 = *(const bf16x8*)(ab0 + ((unsigned)(2 * 64 + kgrp * 16) ^ swzR));
            bf16x8 a3 = *(const bf16x8*)(ab0 + ((unsigned)(3 * 64 + kgrp * 16) ^ swzR));
            acc0 = __builtin_amdgcn_mfma_f32_16x16x32_bf16(a0, b0, acc0, 0, 0, 0);
            acc0 = __builtin_amdgcn_mfma_f32_16x16x32_bf16(a1, b1, acc0, 0, 0, 0);
            acc0 = __builtin_amdgcn_mfma_f32_16x16x32_bf16(a2, b2, acc0, 0, 0, 0);
            acc0 = __builtin_amdgcn_mfma_f32_16x16x32_bf16(a3, b3, acc0, 0, 0, 0);
        }
        {
            bf16x8 a0 = *(const bf16x8*)(ab1 + ((unsigned)(0 * 64 + kgrp * 16) ^ swzR));
            bf16x8 a1 = *(const bf16x8*)(ab1 + ((unsigned)(1 * 64 + kgrp * 16) ^ swzR));
            bf16x8 a2 = *(const bf16x8*)(ab1 + ((unsigned)(2 * 64 + kgrp * 16) ^ swzR));
            bf16x8 a3 = *(const bf16x8*)(ab1 + ((unsigned)(3 * 64 + kgrp * 16) ^ swzR));
            acc1 = __builtin_amdgcn_mfma_f32_16x16x32_bf16(a0, b0, acc1, 0, 0, 0);
            acc1 = __builtin_amdgcn_mfma_f32_16x16x32_bf16(a1, b1, acc1, 0, 0, 0);
            acc1 = __builtin_amdgcn_mfma_f32_16x16x32_bf16(a2, b2, acc1, 0, 0, 0);
            acc1 = __builtin_amdgcn_mfma_f32_16x16x32_bf16(a3, b3, acc1, 0, 0, 0);
        }
    }
    {   // root source from global Xb: upper half kk 2,3; lower kk 0,1
        int arow0 = blk0 + lrow;      if (arow0 >= N) arow0 = N - 1;
        int arow1 = blk0 + 16 + lrow; if (arow1 >= N) arow1 = N - 1;
        const ushort* A0 = Xb + (size_t)arow0 * 128;
        const ushort* A1 = Xb + (size_t)arow1 * 128;
        const bf16x8* Bp = Wf8 + (size_t)8 * 2048 + (size_t)n0 * 64 + lane;
        int kkb = upper * 2;
        bf16x8 b0 = Bp[(kkb + 0) * 512];
        bf16x8 b1 = Bp[(kkb + 1) * 512];
        bf16x8 a00 = *(const bf16x8*)(A0 + (kkb + 0) * 32 + kgrp * 8);
        bf16x8 a01 = *(const bf16x8*)(A0 + (kkb + 1) * 32 + kgrp * 8);
        bf16x8 a10 = *(const bf16x8*)(A1 + (kkb + 0) * 32 + kgrp * 8);
        bf16x8 a11 = *(const bf16x8*)(A1 + (kkb + 1) * 32 + kgrp * 8);
        acc0 = __builtin_amdgcn_mfma_f32_16x16x32_bf16(a00, b0, acc0, 0, 0, 0);
        acc0 = __builtin_amdgcn_mfma_f32_16x16x32_bf16(a01, b1, acc0, 0, 0, 0);
        acc1 = __builtin_amdgcn_mfma_f32_16x16x32_bf16(a10, b0, acc1, 0, 0, 0);
        acc1 = __builtin_amdgcn_mfma_f32_16x16x32_bf16(a11, b1, acc1, 0, 0, 0);
    }

    if (upper) {
        pscr[0][n0 * 64 + lane] = acc0;
        pscr[1][n0 * 64 + lane] = acc1;
    }
    __syncthreads();   // after this, ALL A-tile reads are complete

    if (!upper) {
        f32x4 p0 = pscr[0][n0 * 64 + lane];
        f32x4 p1 = pscr[1][n0 * 64 + lane];
        int col = n0 * 16 + lrow;
        float bv = bias[col];
        float* embt = (float*)lds;   // reuse A-tile LDS (16 KB of 64)
        #pragma unroll
        for (int rg = 0; rg < 2; rg++) {
            int lrowb = rg * 16 + kgrp * 4;
            f32x4 a = rg ? acc1 : acc0;
            f32x4 pp = rg ? p1 : p0;
            #pragma unroll
            for (int r = 0; r < 4; r++) {
                int row = blk0 + lrowb + r;
                float v = a[r] + pp[r] + bv;
                if (relu) v = fmaxf(v, 0.f);
                if (outC) embt[(lrowb + r) * 128 + col] = v;
                if (row < N) {
                    if (Ofp) Ofp[(size_t)row * 128 + col] = v;
                    if (Obf) Obf[(size_t)row * 128 + col] = f2bf(v);
                }
            }
        }
    }

    // ---------------- fused classifier (layer 2 only) ----------------
    if (outC) {
        __syncthreads();
        int t = threadIdx.x;
        if (t < 512) {
            int row = t >> 4;
            int c = t & 15;
            const float* er = (const float*)lds + row * 128;
            float acc2 = bc[c];
            #pragma unroll 8
            for (int k = 0; k < 128; k++) acc2 += er[k] * Wc[k * 16 + c];
            int grow = blk0 + row;
            if (grow < N) outC[(size_t)grow * 16 + c] = acc2;
        }
    }
}

static inline size_t align256(size_t x) { return (x + 255) & ~(size_t)255; }

extern "C" void kernel_launch(void* const* d_in, const int* in_sizes, int n_in,
                              void* d_out, int out_size, void* d_ws, size_t ws_size,
                              hipStream_t stream)
{
    const float* x     = (const float*)d_in[0];
    const int*   ei    = (const int*)d_in[1];
    const int*   et    = (const int*)d_in[2];
    const float* W1    = (const float*)d_in[3];
    const float* root1 = (const float*)d_in[4];
    const float* b1    = (const float*)d_in[5];
    const float* W2    = (const float*)d_in[6];
    const float* root2 = (const float*)d_in[7];
    const float* b2    = (const float*)d_in[8];
    const float* Wc    = (const float*)d_in[9];
    const float* bc    = (const float*)d_in[10];

    const int N = in_sizes[0] / 128;
    const int E = in_sizes[2];
    const int C = in_sizes[10];   // 16

    float* out = (float*)d_out;                 // [N,16]
    float* emb = out + (size_t)N * C;           // [N,128] fp32 (2nd output)

    // ws: cnt | rowptr | cursor | part | bsum | invc8 | spk | xb | hb | Wf1 | Wf2
    size_t cntB  = align256((size_t)NREL * N * sizeof(int));
    size_t rpB   = align256((size_t)(N + 1) * sizeof(int));
    size_t curB  = align256((size_t)N * sizeof(int));
    size_t bsB   = align256((size_t)1024 * sizeof(int));
    size_t invB  = align256((size_t)N * 8 * sizeof(float));
    size_t spkB  = align256((size_t)E * sizeof(int));
    size_t xbB   = align256((size_t)N * 128 * sizeof(ushort));
    size_t wtB   = align256((size_t)128 * 1152 * sizeof(ushort));

    char* p = (char*)d_ws;
    int*    cnt    = (int*)p;      p += cntB;
    int*    rowptr = (int*)p;      p += rpB;
    int*    cursor = (int*)p;      p += curB;
    int*    part   = (int*)p;      p += curB;
    int*    bsum   = (int*)p;      p += bsB;
    float*  invc8  = (float*)p;    p += invB;
    int*    spk    = (int*)p;      p += spkB;
    ushort* xb     = (ushort*)p;   p += xbB;
    ushort* hb     = (ushort*)p;   p += xbB;
    ushort* Wf1    = (ushort*)p;   p += wtB;
    ushort* Wf2    = (ushort*)p;

    dim3 blk(256);
    int gE    = (E + 255) / 256;
    int gN    = (N + 255) / 256;     // <=1024 for scan2
    int gFus  = (N + 31) / 32;       // 1563 blocks of 1024 threads
    long long cnt4 = (long long)NREL * N / 4;
    int nx4 = N * 32;

    // ---- prep: zero cnt + bf16 conversions (one kernel) ----
    prep1<<<2048, blk, 0, stream>>>((float4*)cnt, (int)cnt4,
                                    x, xb, nx4,
                                    W1, root1, Wf1, W2, root2, Wf2);

    // ---- CSR build (shared by both layers) ----
    count_edges<<<gE, blk, 0, stream>>>(ei, et, cnt, E, N);
    scan1f<<<gN, blk, 0, stream>>>(cnt, invc8, part, bsum, N);
    scan2<<<1, 1024, 0, stream>>>(bsum, gN);
    scan3<<<gN, blk, 0, stream>>>(part, bsum, rowptr, cursor, N, E);
    fill_csr<<<gE, blk, 0, stream>>>(ei, et, cursor, spk, E);

    // ---- layer 1: fused gather+GEMM -> hb (bf16, relu) ----
    fused_layer<<<gFus, dim3(1024), 0, stream>>>(
        xb, rowptr, spk, invc8, Wf1, b1, nullptr, hb,
        nullptr, nullptr, nullptr, N, 1);

    // ---- layer 2: fused gather+GEMM+classifier -> emb + out ----
    fused_layer<<<gFus, dim3(1024), 0, stream>>>(
        hb, rowptr, spk, invc8, Wf2, b2, emb, nullptr,
        Wc, bc, out, N, 0);
}